// Round 13
// baseline (126.316 us; speedup 1.0000x reference)
//
#include <hip/hip_runtime.h>
#include <math.h>

#define N 512
#define CS 384
#define CP 128
#define CH 16
#define NH 12
#define NN (N*N)
#define DCAT 2112
#define INFV 100000.0f

__device__ __constant__ float SC_QK = 0.14433756729740643f; // sqrt(1/48)
#define SC_B  0.57735026918962576f  // sqrt(1/3)
#define HW_SC 0.13608276348795434f  // sqrt(1/54)

typedef __attribute__((ext_vector_type(8))) short bf16x8;
typedef __attribute__((ext_vector_type(4))) float f32x4;
typedef __attribute__((ext_vector_type(4))) short sh4;
typedef __attribute__((ext_vector_type(4))) unsigned u32x4;
typedef unsigned short ushort_t;

__device__ inline short f2bf(float v) {
    unsigned u = __builtin_bit_cast(unsigned, v);
    u += 0x7FFF + ((u >> 16) & 1);   // round-to-nearest-even
    return (short)(u >> 16);
}
__device__ inline float bf2f(ushort_t u) {
    unsigned x = ((unsigned)u) << 16;
    return __builtin_bit_cast(float, x);
}
// packs {lo16: bf16(a), hi16: bf16(b)}
__device__ __forceinline__ unsigned cvtpk(float a, float b) {
    unsigned r;
    asm("v_cvt_pk_bf16_f32 %0, %1, %2" : "=v"(r) : "v"(a), "v"(b));
    return r;
}

__device__ __forceinline__ void gload16(const void* g, void* l) {
    __builtin_amdgcn_global_load_lds(
        (const __attribute__((address_space(1))) unsigned int*)g,
        (__attribute__((address_space(3))) unsigned int*)l,
        16, 0, 0);
}

// ============ front: bias_mfma (blocks 0..4095) + prep (blocks 4096..5956) ============
struct FrontArgs {
    const float* wsrc0; const float* wsrc1; const float* wsrc2; const float* wsrc3;
    const float* wsrc4; const float* wsrc5; const float* wsrc6; const float* wsrc7;
    ushort_t* wdst0; ushort_t* wdst1; ushort_t* wdst2; ushort_t* wdst3;
    ushort_t* wdst4; ushort_t* wdst5; ushort_t* wdst6; ushort_t* wdst7;
    const float* s; ushort_t* sbf;
    const float* bq; const float* bkv; const float* bqp; const float* bkvp;
    float* biasp;
    const float* p; const float* w_b; const float* b_b; ushort_t* bias_b;
};

__global__ __launch_bounds__(256) void front_kernel(FrontArgs a)
{
    __shared__ __align__(16) char SM[36864];
    const int b = blockIdx.x;
    const int t = threadIdx.x;
    if (b < 4096) {
        // ---- bias via MFMA (gload16 f32 staging) -> bias_b bf16 ----
        float* Pf = (float*)SM;                      // 32 KB
        ushort_t* Wbs = (ushort_t*)(SM + 32768);     // 4 KB
        const int w = t >> 6;
        const size_t row0 = (size_t)b * 64;

        for (int idx = t; idx < 2048; idx += 256) {
            int h = idx >> 7, c = idx & 127;
            float v = (h < 12) ? a.w_b[c * 12 + h] : 0.f;
            int byte = h * 256 + ((c * 2) ^ ((h & 7) << 4));
            *(ushort_t*)((char*)Wbs + byte) = (ushort_t)f2bf(v);
        }
        #pragma unroll
        for (int k = 0; k < 8; ++k) {
            int s2 = k * 256 + t;
            int row = s2 >> 5, ch = s2 & 31;
            const char* src = (const char*)(a.p + (row0 + row) * 128) + ((ch ^ (row & 7)) * 16);
            gload16(src, (char*)Pf + (size_t)(k * 256 + w * 64) * 16);
        }
        __syncthreads();

        const int l = t & 63, lr = l & 15, hk = l >> 4;
        const int jb = w * 16;
        f32x4 acc = (f32x4){0.f, 0.f, 0.f, 0.f};
        #pragma unroll
        for (int ks = 0; ks < 4; ++ks) {
            int row = jb + lr;
            int kc = ks * 8 + hk * 2;
            const char* base = (const char*)Pf + row * 512;
            f32x4 v0 = *(const f32x4*)(base + ((kc ^ (row & 7)) * 16));
            f32x4 v1 = *(const f32x4*)(base + (((kc + 1) ^ (row & 7)) * 16));
            bf16x8 afr;
            afr[0] = f2bf(v0[0]); afr[1] = f2bf(v0[1]); afr[2] = f2bf(v0[2]); afr[3] = f2bf(v0[3]);
            afr[4] = f2bf(v1[0]); afr[5] = f2bf(v1[1]); afr[6] = f2bf(v1[2]); afr[7] = f2bf(v1[3]);
            bf16x8 bfr = *(const bf16x8*)((char*)Wbs + lr * 256 +
                            ((ks * 64 + hk * 16) ^ ((lr & 7) << 4)));
            acc = __builtin_amdgcn_mfma_f32_16x16x32_bf16(afr, bfr, acc, 0, 0, 0);
        }
        if (lr < 12) {
            float bb = a.b_b[lr];
            size_t gj = row0 + jb + hk * 4;
            sh4 o;
            #pragma unroll
            for (int r = 0; r < 4; ++r) o[r] = f2bf(SC_B * (acc[r] + bb));
            *(sh4*)(a.bias_b + (size_t)lr * NN + gj) = o;
        }
    } else {
        const int bp = b - 4096;
        if (bp < 1668) {
            const float* src; ushort_t* dst; int begin, nx, Nc, K;
            if      (bp < 72)   { src=a.wsrc0; dst=a.wdst0; begin=0;    nx=6;  Nc=192; K=384; }
            else if (bp < 216)  { src=a.wsrc1; dst=a.wdst1; begin=72;   nx=12; Nc=384; K=384; }
            else if (bp < 276)  { src=a.wsrc2; dst=a.wdst2; begin=216;  nx=5;  Nc=144; K=384; }
            else if (bp < 444)  { src=a.wsrc3; dst=a.wdst3; begin=276;  nx=14; Nc=432; K=384; }
            else if (bp < 1236) { src=a.wsrc4; dst=a.wdst4; begin=444;  nx=12; Nc=384; K=2112; }
            else if (bp < 1380) { src=a.wsrc5; dst=a.wdst5; begin=1236; nx=12; Nc=384; K=384; }
            else if (bp < 1524) { src=a.wsrc6; dst=a.wdst6; begin=1380; nx=12; Nc=384; K=384; }
            else                { src=a.wsrc7; dst=a.wdst7; begin=1524; nx=12; Nc=384; K=384; }
            int lb = bp - begin;
            int cx = (lb % nx) * 32, ky = (lb / nx) * 32;
            float (*tile)[33] = (float(*)[33])SM;
            const int tx = t & 31, ty = t >> 5;
            for (int r = ty; r < 32; r += 8) {
                int c = cx + tx;
                tile[r][tx] = (c < Nc) ? src[(size_t)(ky + r) * Nc + c] : 0.f;
            }
            __syncthreads();
            for (int r = ty; r < 32; r += 8) {
                int orow = cx + r;
                if (orow < Nc)
                    dst[(size_t)orow * K + ky + tx] = (ushort_t)f2bf(tile[tx][r]);
            }
        } else if (bp < 1860) {
            int i4 = (bp - 1668) * 256 + t;
            f32x4 v = *(const f32x4*)(a.s + (size_t)i4 * 4);
            sh4 o;
            o[0] = f2bf(v[0]); o[1] = f2bf(v[1]); o[2] = f2bf(v[2]); o[3] = f2bf(v[3]);
            *(sh4*)(a.sbf + (size_t)i4 * 4) = o;
        } else {
            for (int idx = t; idx < 1152; idx += 256) {
                float v;
                if (idx < 192)      v = a.bq[idx];
                else if (idx < 576) v = a.bkv[idx - 192];
                else if (idx < 720) v = a.bqp[idx - 576];
                else                v = a.bkvp[idx - 720];
                a.biasp[idx] = v;
            }
        }
    }
}

// ============ bf16 MFMA GEMM, 64x64 tile, BK=32, 2-phase pipelined, split-K ============
__global__ __launch_bounds__(256) void gemm_bf16(
    const ushort_t* __restrict__ A, const ushort_t* __restrict__ Bt,
    float* __restrict__ part, int K, int KOUT, int nk)
{
    __shared__ __align__(16) ushort_t As[2][2048];
    __shared__ __align__(16) ushort_t Bs[2][2048];
    const int t = threadIdx.x, w = t >> 6, l = t & 63;
    const int i0 = blockIdx.x * 64, n0 = blockIdx.y * 64, sp = blockIdx.z;
    const int kbase = sp * nk * 32;

    const int srow = w * 16 + (l >> 2);
    const int skb = (l & 3) ^ ((srow >> 1) & 3);
    const ushort_t* aSrc = A + (size_t)(i0 + srow) * K + kbase + skb * 8;
    const ushort_t* bSrc = Bt + (size_t)(n0 + srow) * K + kbase + skb * 8;
    ushort_t* aDst = &As[0][0] + w * 512;
    ushort_t* bDst = &Bs[0][0] + w * 512;

    const int r0 = (w >> 1) * 32, c0 = (w & 1) * 32, lr = l & 15, hk = l >> 4;
    int aOff[2], bOff[2];
    #pragma unroll
    for (int m = 0; m < 2; ++m) {
        int row = r0 + m * 16 + lr;
        aOff[m] = row * 64 + ((hk ^ ((row >> 1) & 3)) << 4);
    }
    #pragma unroll
    for (int n = 0; n < 2; ++n) {
        int row = c0 + n * 16 + lr;
        bOff[n] = row * 64 + ((hk ^ ((row >> 1) & 3)) << 4);
    }

    f32x4 acc[2][2];
    #pragma unroll
    for (int m = 0; m < 2; ++m)
        #pragma unroll
        for (int n = 0; n < 2; ++n) acc[m][n] = (f32x4){0.f, 0.f, 0.f, 0.f};

    gload16(aSrc, aDst);
    gload16(bSrc, bDst);
    __syncthreads();

    int cur = 0;
    for (int it = 0; it < nk; ++it) {
        if (it + 1 < nk) {
            gload16(aSrc + (it + 1) * 32, aDst + (cur ^ 1) * 2048);
            gload16(bSrc + (it + 1) * 32, bDst + (cur ^ 1) * 2048);
        }
        const char* ab = (const char*)&As[cur][0];
        const char* bb = (const char*)&Bs[cur][0];
        bf16x8 a0 = *(const bf16x8*)(ab + aOff[0]);
        bf16x8 a1 = *(const bf16x8*)(ab + aOff[1]);
        bf16x8 b0 = *(const bf16x8*)(bb + bOff[0]);
        bf16x8 b1 = *(const bf16x8*)(bb + bOff[1]);
        acc[0][0] = __builtin_amdgcn_mfma_f32_16x16x32_bf16(a0, b0, acc[0][0], 0, 0, 0);
        acc[0][1] = __builtin_amdgcn_mfma_f32_16x16x32_bf16(a0, b1, acc[0][1], 0, 0, 0);
        acc[1][0] = __builtin_amdgcn_mfma_f32_16x16x32_bf16(a1, b0, acc[1][0], 0, 0, 0);
        acc[1][1] = __builtin_amdgcn_mfma_f32_16x16x32_bf16(a1, b1, acc[1][1], 0, 0, 0);
        __syncthreads();
        cur ^= 1;
    }

    #pragma unroll
    for (int m = 0; m < 2; ++m)
        #pragma unroll
        for (int n = 0; n < 2; ++n) {
            int col = n0 + c0 + n * 16 + lr;
            int rowb = i0 + r0 + m * 16 + (l >> 4) * 4;
            float* pr = part + ((size_t)sp * 512 + rowb) * KOUT + col;
            #pragma unroll
            for (int j = 0; j < 4; ++j)
                pr[(size_t)j * KOUT] = acc[m][n][j];
        }
}

// ============ gemm_red: A = relu(sum of 3 partials + kbias), K=384; B via gload16 ==========
__global__ __launch_bounds__(256) void gemm_red(
    const float* __restrict__ partsIn, const float* __restrict__ kbias,
    const ushort_t* __restrict__ Bt, float* __restrict__ partOut, int nk)
{
    __shared__ __align__(16) ushort_t As[2][2048];
    __shared__ __align__(16) ushort_t Bs[2][2048];
    const int t = threadIdx.x, w = t >> 6, l = t & 63;
    const int i0 = blockIdx.x * 64, n0 = blockIdx.y * 64, sp = blockIdx.z;
    const int kbase = sp * nk * 32;

    const int srow = w * 16 + (l >> 2);
    const int skb = (l & 3) ^ ((srow >> 1) & 3);
    const ushort_t* bSrc = Bt + (size_t)(n0 + srow) * 384 + kbase + skb * 8;
    ushort_t* bDst = &Bs[0][0] + w * 512;

    const int ar = t >> 2, apch = t & 3;
    const int agch = apch ^ ((ar >> 1) & 3);
    const float* aBase = partsIn + (size_t)(i0 + ar) * 384 + kbase + agch * 8;
    const int aByte = ar * 64 + apch * 16;

    const int r0 = (w >> 1) * 32, c0 = (w & 1) * 32, lr = l & 15, hk = l >> 4;
    int aOff[2], bOff[2];
    #pragma unroll
    for (int m = 0; m < 2; ++m) {
        int row = r0 + m * 16 + lr;
        aOff[m] = row * 64 + ((hk ^ ((row >> 1) & 3)) << 4);
    }
    #pragma unroll
    for (int n = 0; n < 2; ++n) {
        int row = c0 + n * 16 + lr;
        bOff[n] = row * 64 + ((hk ^ ((row >> 1) & 3)) << 4);
    }

    f32x4 av0, av1;
    #define A_LOAD(it)                                                            \
        {                                                                         \
            const float* ap = aBase + (it) * 32;                                  \
            av0 = *(const f32x4*)(ap) + *(const f32x4*)(ap + 196608)              \
                + *(const f32x4*)(ap + 393216);                                   \
            av1 = *(const f32x4*)(ap + 4) + *(const f32x4*)(ap + 196608 + 4)      \
                + *(const f32x4*)(ap + 393216 + 4);                               \
        }
    #define A_STORE(buf, it)                                                      \
        {                                                                         \
            int kk = kbase + (it) * 32 + agch * 8;                                \
            f32x4 kb0 = *(const f32x4*)(kbias + kk);                              \
            f32x4 kb1 = *(const f32x4*)(kbias + kk + 4);                          \
            f32x4 s0 = av0 + kb0, s1 = av1 + kb1;                                 \
            u32x4 pk;                                                             \
            pk[0] = cvtpk(fmaxf(s0[0], 0.f), fmaxf(s0[1], 0.f));                  \
            pk[1] = cvtpk(fmaxf(s0[2], 0.f), fmaxf(s0[3], 0.f));                  \
            pk[2] = cvtpk(fmaxf(s1[0], 0.f), fmaxf(s1[1], 0.f));                  \
            pk[3] = cvtpk(fmaxf(s1[2], 0.f), fmaxf(s1[3], 0.f));                  \
            *(u32x4*)((char*)&As[buf][0] + aByte) = pk;                           \
        }

    f32x4 acc[2][2];
    #pragma unroll
    for (int m = 0; m < 2; ++m)
        #pragma unroll
        for (int n = 0; n < 2; ++n) acc[m][n] = (f32x4){0.f, 0.f, 0.f, 0.f};

    gload16(bSrc, bDst);
    A_LOAD(0);
    A_STORE(0, 0);
    __syncthreads();

    int cur = 0;
    for (int it = 0; it < nk; ++it) {
        if (it + 1 < nk) {
            gload16(bSrc + (it + 1) * 32, bDst + (cur ^ 1) * 2048);
            A_LOAD(it + 1);
        }
        const char* ab = (const char*)&As[cur][0];
        const char* bb = (const char*)&Bs[cur][0];
        bf16x8 a0 = *(const bf16x8*)(ab + aOff[0]);
        bf16x8 a1 = *(const bf16x8*)(ab + aOff[1]);
        bf16x8 b0 = *(const bf16x8*)(bb + bOff[0]);
        bf16x8 b1 = *(const bf16x8*)(bb + bOff[1]);
        acc[0][0] = __builtin_amdgcn_mfma_f32_16x16x32_bf16(a0, b0, acc[0][0], 0, 0, 0);
        acc[0][1] = __builtin_amdgcn_mfma_f32_16x16x32_bf16(a0, b1, acc[0][1], 0, 0, 0);
        acc[1][0] = __builtin_amdgcn_mfma_f32_16x16x32_bf16(a1, b0, acc[1][0], 0, 0, 0);
        acc[1][1] = __builtin_amdgcn_mfma_f32_16x16x32_bf16(a1, b1, acc[1][1], 0, 0, 0);
        if (it + 1 < nk) A_STORE(cur ^ 1, it + 1);
        __syncthreads();
        cur ^= 1;
    }
    #undef A_LOAD
    #undef A_STORE

    #pragma unroll
    for (int m = 0; m < 2; ++m)
        #pragma unroll
        for (int n = 0; n < 2; ++n) {
            int col = n0 + c0 + n * 16 + lr;
            int rowb = i0 + r0 + m * 16 + (l >> 4) * 4;
            float* pr = partOut + ((size_t)sp * 512 + rowb) * 384 + col;
            #pragma unroll
            for (int j = 0; j < 4; ++j)
                pr[(size_t)j * 384] = acc[m][n][j];
        }
}

// ============ fused reduce split-K + bias + resid + LayerNorm (+ optional rigid update) ====
__global__ void reduce_ln(const float* __restrict__ parts, int S,
                          const float* __restrict__ gbias, const float* __restrict__ resid,
                          const float* __restrict__ g, const float* __restrict__ b,
                          float* __restrict__ outf, ushort_t* __restrict__ outbf,
                          const float* __restrict__ bb_w, const float* __restrict__ bb_b,
                          const float* __restrict__ rot, const float* __restrict__ trans,
                          float* __restrict__ out_rot, float* __restrict__ out_trans)
{
    __shared__ float buf[384];
    __shared__ float red[2], red2[2];
    __shared__ float ush[2][6];
    const int i = blockIdx.x, t = threadIdx.x;  // 128 threads
    float s = 0.f, sq = 0.f;
    for (int k = t; k < 384; k += 128) {
        float v = gbias[k] + resid[(size_t)i * 384 + k];
        for (int s2 = 0; s2 < S; ++s2)
            v += parts[((size_t)s2 * 512 + i) * 384 + k];
        buf[k] = v; s += v; sq += v * v;
    }
    for (int off = 32; off; off >>= 1) { s += __shfl_xor(s, off); sq += __shfl_xor(sq, off); }
    if ((t & 63) == 0) { red[t >> 6] = s; red2[t >> 6] = sq; }
    __syncthreads();
    float mean = (red[0] + red[1]) * (1.0f / 384.0f);
    float var = (red2[0] + red2[1]) * (1.0f / 384.0f) - mean * mean;
    float rstd = rsqrtf(var + 1e-5f);
    float onorm[3];
    #pragma unroll
    for (int kk = 0; kk < 3; ++kk) {
        int k = t + kk * 128;
        float o = (buf[k] - mean) * rstd * g[k] + b[k];
        onorm[kk] = o;
        if (outf) outf[(size_t)i * 384 + k] = o;
        if (outbf) outbf[(size_t)i * 384 + k] = (ushort_t)f2bf(o);
    }
    if (!bb_w) return;
    float u[6] = {0.f, 0.f, 0.f, 0.f, 0.f, 0.f};
    #pragma unroll
    for (int kk = 0; kk < 3; ++kk) {
        int k = t + kk * 128;
        float sv = onorm[kk];
        #pragma unroll
        for (int c = 0; c < 6; ++c) u[c] += sv * bb_w[k * 6 + c];
    }
    #pragma unroll
    for (int c = 0; c < 6; ++c)
        for (int off = 32; off; off >>= 1) u[c] += __shfl_xor(u[c], off);
    if ((t & 63) == 0) {
        #pragma unroll
        for (int c = 0; c < 6; ++c) ush[t >> 6][c] = u[c];
    }
    __syncthreads();
    if (t == 0) {
        float uu[6];
        #pragma unroll
        for (int c = 0; c < 6; ++c) uu[c] = ush[0][c] + ush[1][c] + bb_b[c];
        float inq = rsqrtf(1.0f + uu[0]*uu[0] + uu[1]*uu[1] + uu[2]*uu[2]);
        float w = inq, x = uu[0]*inq, y = uu[1]*inq, z = uu[2]*inq;
        float Ru[9];
        Ru[0] = 1.f - 2.f*(y*y + z*z); Ru[1] = 2.f*(x*y - w*z); Ru[2] = 2.f*(x*z + w*y);
        Ru[3] = 2.f*(x*y + w*z); Ru[4] = 1.f - 2.f*(x*x + z*z); Ru[5] = 2.f*(y*z - w*x);
        Ru[6] = 2.f*(x*z - w*y); Ru[7] = 2.f*(y*z + w*x); Ru[8] = 1.f - 2.f*(x*x + y*y);
        const float* R = rot + i * 9;
        #pragma unroll
        for (int a = 0; a < 3; ++a) {
            #pragma unroll
            for (int cc = 0; cc < 3; ++cc)
                out_rot[i * 9 + a * 3 + cc] =
                    R[a*3+0]*Ru[0+cc] + R[a*3+1]*Ru[3+cc] + R[a*3+2]*Ru[6+cc];
            out_trans[i * 3 + a] = R[a*3+0]*uu[3] + R[a*3+1]*uu[4] + R[a*3+2]*uu[5]
                                   + trans[i * 3 + a];
        }
    }
}

// ============ postproj: reduce proj partials + rotate points + emit Qext/Kext/Vext ========
__global__ __launch_bounds__(256) void postproj_kernel(
    const float* __restrict__ parts, const float* __restrict__ biasp,
    const float* __restrict__ rot, const float* __restrict__ trans,
    const float* __restrict__ head_w, const float* __restrict__ mask,
    ushort_t* __restrict__ Qext, ushort_t* __restrict__ Kext, ushort_t* __restrict__ Vext)
{
    __shared__ float buf[1152];
    __shared__ float hwv[12], kc28[12];
    const int j = blockIdx.x, t = threadIdx.x;
    for (int c = t; c < 1152; c += 256)
        buf[c] = biasp[c] + parts[(size_t)j * 1152 + c] + parts[(size_t)(512 + j) * 1152 + c];
    if (t >= 192 && t < 204) {
        int h = t - 192;
        hwv[h] = HW_SC * log1pf(expf(head_w[h]));
    }
    __syncthreads();
    if (t < 192) {
        int base = 576 + t * 3;
        const float* R = rot + j * 9;
        const float* T = trans + j * 3;
        float x = buf[base], y = buf[base + 1], z = buf[base + 2];
        float nx = R[0]*x + R[1]*y + R[2]*z + T[0];
        float ny = R[3]*x + R[4]*y + R[5]*z + T[1];
        float nz = R[6]*x + R[7]*y + R[8]*z + T[2];
        buf[base] = nx; buf[base + 1] = ny; buf[base + 2] = nz;
    }
    __syncthreads();
    if (t < 12) {
        float s2 = 0.f;
        #pragma unroll
        for (int e = 0; e < 12; ++e) { float v = buf[720 + t * 36 + e]; s2 += v * v; }
        kc28[t] = -0.5f * hwv[t] * s2 + (mask[j] - 1.0f) * INFV;
    }
    __syncthreads();
    if (t < 192) {
        int h = t >> 4, c0 = (t & 15) * 2;
        float hwf = hwv[h];
        #pragma unroll
        for (int e = 0; e < 2; ++e) {
            int c = c0 + e;
            float qv, kv2;
            if (c < 16)      { qv = SC_QK * buf[h * 16 + c];           kv2 = buf[192 + h * 32 + c]; }
            else if (c < 28) { qv = hwf * buf[576 + h * 12 + (c - 16)]; kv2 = buf[720 + h * 36 + (c - 16)]; }
            else if (c == 28){ qv = 1.f;                               kv2 = kc28[h]; }
            else             { qv = 0.f;                               kv2 = 0.f; }
            Qext[(size_t)h * 16384 + j * 32 + c] = (ushort_t)f2bf(qv);
            Kext[(size_t)h * 16384 + j * 32 + c] = (ushort_t)f2bf(kv2);
        }
    }
    for (int idx = t; idx < 576; idx += 256) {
        int h = idx / 48, c = idx % 48;
        float v;
        if (c < 16)      v = buf[192 + h * 32 + 16 + c];
        else if (c < 40) v = buf[720 + h * 36 + 12 + (c - 16)];
        else             v = 0.f;
        Vext[(size_t)h * 24576 + c * 512 + j] = (ushort_t)f2bf(v);
    }
}

// ============ attn logits via MFMA + softmax + fused A@V + op finalize ============
__global__ __launch_bounds__(256) void attn_mfma(
    const ushort_t* __restrict__ Qext, const ushort_t* __restrict__ Kext,
    const ushort_t* __restrict__ bias_b, const ushort_t* __restrict__ Vext,
    const float* __restrict__ rot, const float* __restrict__ trans,
    ushort_t* __restrict__ attn_b, ushort_t* __restrict__ catb)
{
    __shared__ float sc[16 * 516];
    __shared__ float redm[64];
    __shared__ float invr[16];
    __shared__ float opl[16][25];
    const int t = threadIdx.x, w = t >> 6, l = t & 63;
    const int i0 = blockIdx.x * 16, h = blockIdx.y;
    const int lr = l & 15, hk = l >> 4;

    #pragma unroll
    for (int it = 0; it < 8; ++it) {
        int elem = (t + it * 256) * 4;
        int i = elem >> 9, j = elem & 511;
        sh4 raw = *(const sh4*)(bias_b + (size_t)h * NN + (size_t)(i0 + i) * 512 + j);
        f32x4 v;
        v[0] = bf2f((ushort_t)raw[0]); v[1] = bf2f((ushort_t)raw[1]);
        v[2] = bf2f((ushort_t)raw[2]); v[3] = bf2f((ushort_t)raw[3]);
        *(f32x4*)(sc + i * 516 + j) = v;
    }
    __syncthreads();

    bf16x8 a0 = *(const bf16x8*)(Qext + (size_t)h * 16384 + (i0 + lr) * 32 + hk * 8);
    f32x4 acc[8];
    #pragma unroll
    for (int n = 0; n < 8; ++n) {
        bf16x8 b = *(const bf16x8*)(Kext + (size_t)h * 16384 +
                                    (w * 128 + n * 16 + lr) * 32 + hk * 8);
        acc[n] = __builtin_amdgcn_mfma_f32_16x16x32_bf16(a0, b, (f32x4){0.f,0.f,0.f,0.f}, 0, 0, 0);
    }

    float rmax[4] = {-3.0e38f, -3.0e38f, -3.0e38f, -3.0e38f};
    #pragma unroll
    for (int n = 0; n < 8; ++n) {
        int col = w * 128 + n * 16 + lr;
        #pragma unroll
        for (int r = 0; r < 4; ++r) {
            int row = hk * 4 + r;
            float v = acc[n][r] + sc[row * 516 + col];
            sc[row * 516 + col] = v;
            rmax[r] = fmaxf(rmax[r], v);
        }
    }
    #pragma unroll
    for (int r = 0; r < 4; ++r) {
        float v = rmax[r];
        v = fmaxf(v, __shfl_xor(v, 1));
        v = fmaxf(v, __shfl_xor(v, 2));
        v = fmaxf(v, __shfl_xor(v, 4));
        v = fmaxf(v, __shfl_xor(v, 8));
        if (lr == 0) redm[w * 16 + hk * 4 + r] = v;
    }
    __syncthreads();

    {
        int row = t >> 4, g = t & 15;
        float mx = fmaxf(fmaxf(redm[row], redm[16 + row]),
                         fmaxf(redm[32 + row], redm[48 + row]));
        float sum = 0.f;
        float* sr = sc + row * 516;
        for (int c = g; c < 512; c += 16) {
            float e = expf(sr[c] - mx);
            sr[c] = e;
            sum += e;
        }
        sum += __shfl_xor(sum, 1);
        sum += __shfl_xor(sum, 2);
        sum += __shfl_xor(sum, 4);
        sum += __shfl_xor(sum, 8);
        if (g == 0) invr[row] = 1.0f / sum;
    }
    __syncthreads();

    #pragma unroll
    for (int it = 0; it < 8; ++it) {
        int elem = (t + it * 256) * 4;
        int i = elem >> 9, j = elem & 511;
        f32x4 v = *(const f32x4*)(sc + i * 516 + j);
        float iv = invr[i];
        sh4 o;
        o[0] = f2bf(v[0] * iv); o[1] = f2bf(v[1] * iv);
        o[2] = f2bf(v[2] * iv); o[3] = f2bf(v[3] * iv);
        *(sh4*)(attn_b + (size_t)h * NN + (size_t)(i0 + i) * 512 + j) = o;
    }

    f32x4 acc3[3];
    acc3[0] = (f32x4){0.f,0.f,0.f,0.f};
    acc3[1] = (f32x4){0.f,0.f,0.f,0.f};
    acc3[2] = (f32x4){0.f,0.f,0.f,0.f};
    const ushort_t* vbase = Vext + (size_t)h * 24576 + lr * 512 + hk * 8;
    #pragma unroll
    for (int kt = 0; kt < 16; ++kt) {
        const float* srow = sc + lr * 516 + kt * 32 + hk * 8;
        f32x4 x0 = *(const f32x4*)(srow);
        f32x4 x1 = *(const f32x4*)(srow + 4);
        u32x4 ap;
        ap[0] = cvtpk(x0[0], x0[1]); ap[1] = cvtpk(x0[2], x0[3]);
        ap[2] = cvtpk(x1[0], x1[1]); ap[3] = cvtpk(x1[2], x1[3]);
        bf16x8 af = __builtin_bit_cast(bf16x8, ap);
        #pragma unroll
        for (int n = 0; n < 3; ++n) {
            bf16x8 bf = *(const bf16x8*)(vbase + n * 16 * 512 + kt * 32);
            acc3[n] = __builtin_amdgcn_mfma_f32_16x16x32_bf16(af, bf, acc3[n], 0, 0, 0);
        }
    }
    #pragma unroll
    for (int n = 0; n < 3; ++n) {
        int c = n * 16 + lr;
        #pragma unroll
        for (int r = 0; r < 4; ++r) {
            int ri = hk * 4 + r;
            float val = acc3[n][r] * invr[ri];
            if (c < 16)
                catb[(size_t)(i0 + ri) * DCAT + h * 16 + c] = (ushort_t)f2bf(val);
            else if (c < 40)
                opl[ri][c - 16] = val;
        }
    }
    __syncthreads();
    if (t < 128) {
        int i16 = t >> 3, pv = t & 7;
        int i = i0 + i16;
        const float* T = trans + i * 3;
        const float* R = rot + i * 9;
        float x = opl[i16][pv * 3 + 0] - T[0];
        float y = opl[i16][pv * 3 + 1] - T[1];
        float z = opl[i16][pv * 3 + 2] - T[2];
        float rx = R[0] * x + R[3] * y + R[6] * z;
        float ry = R[1] * x + R[4] * y + R[7] * z;
        float rz = R[2] * x + R[5] * y + R[8] * z;
        float nm = sqrtf(rx * rx + ry * ry + rz * rz + 1e-8f);
        ushort_t* cr = catb + (size_t)i * DCAT;
        cr[192 + h * 24 + pv * 3 + 0] = (ushort_t)f2bf(rx);
        cr[192 + h * 24 + pv * 3 + 1] = (ushort_t)f2bf(ry);
        cr[192 + h * 24 + pv * 3 + 2] = (ushort_t)f2bf(rz);
        cr[480 + h * 8 + pv] = (ushort_t)f2bf(nm);
    }
}

// ============ o_pair via MFMA from f32 p (L3-warm), 512 threads = 2 j-groups ============
// Group g owns j in [g*256, g*256+256), 8 tiles of 32 j, own double-buffered Pt.
// Group 1 passes partial acc via LDS; group 0 adds + writes catb. 16 waves/CU.
__global__ __launch_bounds__(512) void opair_mfma(
    const ushort_t* __restrict__ attn_b, const float* __restrict__ p,
    ushort_t* __restrict__ catb)
{
    __shared__ __align__(16) ushort_t As2[16 * 512];        // 16 KB
    __shared__ __align__(16) ushort_t Pt[2][2][128 * 40];   // [group][buf] 40 KB
    __shared__ float scr[2048];                             // 8 KB
    const int t = threadIdx.x, i = blockIdx.x;
    const int g = t >> 8, tl = t & 255;
    const int w = tl >> 6, l = t & 63;
    const int lr = l & 15, hk = l >> 4;
    const int jbase = g * 256;

    // stage A_i -> [16][512] bf16 swizzled (rows 12..15 zero); all 512 threads
    #pragma unroll
    for (int ii = 0; ii < 2; ++ii) {
        int idx = (t + ii * 512) * 8;
        int h = idx >> 9, j = idx & 511;
        bf16x8 v;
        if (h < 12) v = *(const bf16x8*)(attn_b + (size_t)h * NN + (size_t)i * 512 + j);
        else        v = (bf16x8){0,0,0,0,0,0,0,0};
        *(bf16x8*)((char*)As2 + h * 1024 + ((j * 2) ^ ((h & 7) << 4))) = v;
    }

    const int jp = tl >> 4, jl = jp * 2;     // j-pair within 32-j tile
    const int cg = tl & 15, c0 = cg * 8;     // 8 c per thread
    const float* psrc = p + (size_t)i * 65536 + (size_t)jbase * 128;

    f32x4 va[2], vb[2];
    #define LOAD_TILE(tile)                                                      \
        {                                                                        \
            const float* s0 = psrc + (size_t)((tile) * 32 + jl) * 128 + c0;      \
            va[0] = *(const f32x4*)(s0);                                         \
            va[1] = *(const f32x4*)(s0 + 4);                                     \
            vb[0] = *(const f32x4*)(s0 + 128);                                   \
            vb[1] = *(const f32x4*)(s0 + 132);                                   \
        }
    #define PACK_TILE(buf)                                                       \
        {                                                                        \
            ushort_t* ptw = &Pt[g][buf][0];                                      \
            _Pragma("unroll")                                                    \
            for (int e = 0; e < 8; ++e) {                                        \
                int c = c0 + e;                                                  \
                unsigned pk = cvtpk(va[e >> 2][e & 3], vb[e >> 2][e & 3]);       \
                int byte = c * 80 + ((jl * 2) ^ (((c >> 2) & 3) << 4));          \
                *(unsigned*)((char*)ptw + byte) = pk;                            \
            }                                                                    \
        }

    LOAD_TILE(0);
    PACK_TILE(0);
    LOAD_TILE(1);

    f32x4 acc[2];
    acc[0] = (f32x4){0.f, 0.f, 0.f, 0.f};
    acc[1] = (f32x4){0.f, 0.f, 0.f, 0.f};

    int cur = 0;
    for (int tile = 0; tile < 8; ++tile) {
        __syncthreads();   // Pt[g][cur] complete (and As2 on first pass)
        const char* pt = (const char*)&Pt[g][cur][0];
        bf16x8 afr = *(const bf16x8*)((char*)As2 + lr * 1024 +
                        ((jbase * 2 + tile * 64 + hk * 16) ^ ((lr & 7) << 4)));
        #pragma unroll
        for (int n = 0; n < 2; ++n) {
            int c = w * 32 + n * 16 + lr;
            bf16x8 bfr = *(const bf16x8*)(pt + c * 80 +
                            ((hk * 16) ^ (((c >> 2) & 3) << 4)));
            acc[n] = __builtin_amdgcn_mfma_f32_16x16x32_bf16(afr, bfr, acc[n], 0, 0, 0);
        }
        if (tile < 7) {
            PACK_TILE(cur ^ 1);
            if (tile < 6) LOAD_TILE(tile + 2);
            cur ^= 1;
        }
    }
    #undef PACK_TILE
    #undef LOAD_TILE

    // cross-group reduce: group 1 -> LDS, group 0 adds + writes
    if (g == 1) {
        #pragma unroll
        for (int n = 0; n < 2; ++n)
            #pragma unroll
            for (int r = 0; r < 4; ++r)
                scr[((w * 64 + l) * 2 + n) * 4 + r] = acc[n][r];
    }
    __syncthreads();
    if (g == 0) {
        #pragma unroll
        for (int n = 0; n < 2; ++n) {
            int c = w * 32 + n * 16 + lr;
            #pragma unroll
            for (int r = 0; r < 4; ++r) {
                int h = hk * 4 + r;
                float v = acc[n][r] + scr[((w * 64 + l) * 2 + n) * 4 + r];
                if (h < 12)
                    catb[(size_t)i * DCAT + 576 + h * 128 + c] = (ushort_t)f2bf(v);
            }
        }
    }
}

extern "C" void kernel_launch(void* const* d_in, const int* in_sizes, int n_in,
                              void* d_out, int out_size, void* d_ws, size_t ws_size,
                              hipStream_t stream)
{
    const float* s      = (const float*)d_in[0];
    const float* p      = (const float*)d_in[1];
    const float* rot    = (const float*)d_in[2];
    const float* trans  = (const float*)d_in[3];
    const float* mask   = (const float*)d_in[4];
    const float* w_q    = (const float*)d_in[5];
    const float* b_q    = (const float*)d_in[6];
    const float* w_kv   = (const float*)d_in[7];
    const float* b_kv   = (const float*)d_in[8];
    const float* w_qp   = (const float*)d_in[9];
    const float* b_qp   = (const float*)d_in[10];
    const float* w_kvp  = (const float*)d_in[11];
    const float* b_kvp  = (const float*)d_in[12];
    const float* w_b    = (const float*)d_in[13];
    const float* b_b    = (const float*)d_in[14];
    const float* head_w = (const float*)d_in[15];
    const float* w_o    = (const float*)d_in[16];
    const float* b_o    = (const float*)d_in[17];
    const float* ln1_g  = (const float*)d_in[18];
    const float* ln1_b  = (const float*)d_in[19];
    const float* tw1    = (const float*)d_in[20];
    const float* tb1    = (const float*)d_in[21];
    const float* tw2    = (const float*)d_in[22];
    const float* tb2    = (const float*)d_in[23];
    const float* tw3    = (const float*)d_in[24];
    const float* tb3    = (const float*)d_in[25];
    const float* ln2_g  = (const float*)d_in[26];
    const float* ln2_b  = (const float*)d_in[27];
    const float* bb_w   = (const float*)d_in[28];
    const float* bb_b   = (const float*)d_in[29];

    float* ws = (float*)d_ws;
    float*    parts  = ws;                       // 1179648
    float*    partsB = parts + 589824;           // gemm_red ping-pong
    float*    s1     = parts + 1179648;          // 196608
    float*    biasp  = s1 + 196608;              // 1152
    ushort_t* ub     = (ushort_t*)(biasp + 1152);
    ushort_t* bias_b = ub;                       // 3145728
    ushort_t* attn_b = bias_b + 3145728;         // 3145728
    ushort_t* catb   = attn_b + 3145728;         // 1081344
    ushort_t* sbf    = catb + 1081344;           // 196608
    ushort_t* s1bf   = sbf + 196608;
    ushort_t* h1bf   = s1bf + 196608;            // (spare)
    ushort_t* h2bf   = h1bf + 196608;            // (spare)
    ushort_t* Qext   = h2bf + 196608;            // 196608
    ushort_t* Kext   = Qext + 196608;            // 196608
    ushort_t* Vext   = Kext + 196608;            // 294912
    ushort_t* Wtp    = Vext + 294912;            // 442368
    ushort_t* Wto    = Wtp + 442368;             // 811008
    ushort_t* Wt1    = Wto + 811008;             // 147456
    ushort_t* Wt2    = Wt1 + 147456;
    ushort_t* Wt3    = Wt2 + 147456;

    float* out_s     = (float*)d_out;
    float* out_rot   = out_s + 196608;
    float* out_trans = out_rot + 4608;

    // ---- merged front: bias_mfma (4096 blocks) + prep (1861 blocks) ----
    FrontArgs fa;
    fa.wsrc0 = w_q;  fa.wdst0 = Wtp;
    fa.wsrc1 = w_kv; fa.wdst1 = Wtp + (size_t)192 * 384;
    fa.wsrc2 = w_qp; fa.wdst2 = Wtp + (size_t)576 * 384;
    fa.wsrc3 = w_kvp; fa.wdst3 = Wtp + (size_t)720 * 384;
    fa.wsrc4 = w_o;  fa.wdst4 = Wto;
    fa.wsrc5 = tw1;  fa.wdst5 = Wt1;
    fa.wsrc6 = tw2;  fa.wdst6 = Wt2;
    fa.wsrc7 = tw3;  fa.wdst7 = Wt3;
    fa.s = s; fa.sbf = sbf;
    fa.bq = b_q; fa.bkv = b_kv; fa.bqp = b_qp; fa.bkvp = b_kvp;
    fa.biasp = biasp;
    fa.p = p; fa.w_b = w_b; fa.b_b = b_b; fa.bias_b = bias_b;
    front_kernel<<<5957, 256, 0, stream>>>(fa);

    // ---- projection GEMM + fused post-processing ----
    gemm_bf16<<<dim3(8, 18, 2), 256, 0, stream>>>(sbf, Wtp, parts, 384, 1152, 6);
    postproj_kernel<<<512, 256, 0, stream>>>(parts, biasp, rot, trans, head_w, mask,
                                             Qext, Kext, Vext);

    // ---- attention ----
    attn_mfma<<<dim3(32, 12), 256, 0, stream>>>(Qext, Kext, bias_b, Vext, rot, trans,
                                                attn_b, catb);
    opair_mfma<<<512, 512, 0, stream>>>(attn_b, p, catb);

    // ---- output projection + residual + LN1 ----
    gemm_bf16<<<dim3(8, 6, 6), 256, 0, stream>>>(catb, Wto, parts, 2112, 384, 11);
    reduce_ln<<<512, 128, 0, stream>>>(parts, 6, b_o, s, ln1_g, ln1_b, s1, s1bf,
                                       nullptr, nullptr, nullptr, nullptr, nullptr, nullptr);

    // ---- transition: g1 (bf16 path), g2/g3 (fused reduce+relu staging) ----
    gemm_bf16<<<dim3(8, 6, 3), 256, 0, stream>>>(s1bf, Wt1, parts, 384, 384, 4);
    gemm_red<<<dim3(8, 6, 3), 256, 0, stream>>>(parts, tb1, Wt2, partsB, 4);
    gemm_red<<<dim3(8, 6, 3), 256, 0, stream>>>(partsB, tb2, Wt3, parts, 4);
    // LN2 + fused rigid update
    reduce_ln<<<512, 128, 0, stream>>>(parts, 3, tb3, s1, ln2_g, ln2_b, out_s, nullptr,
                                       bb_w, bb_b, rot, trans, out_rot, out_trans);
}

// Round 14
// 124.869 us; speedup vs baseline: 1.0116x; 1.0116x over previous
//
#include <hip/hip_runtime.h>
#include <math.h>

#define N 512
#define CS 384
#define CP 128
#define CH 16
#define NH 12
#define NN (N*N)
#define DCAT 2112
#define INFV 100000.0f

__device__ __constant__ float SC_QK = 0.14433756729740643f; // sqrt(1/48)
#define SC_B  0.57735026918962576f  // sqrt(1/3)
#define HW_SC 0.13608276348795434f  // sqrt(1/54)

typedef __attribute__((ext_vector_type(8))) short bf16x8;
typedef __attribute__((ext_vector_type(4))) float f32x4;
typedef __attribute__((ext_vector_type(4))) short sh4;
typedef __attribute__((ext_vector_type(4))) unsigned u32x4;
typedef unsigned short ushort_t;

__device__ inline short f2bf(float v) {
    unsigned u = __builtin_bit_cast(unsigned, v);
    u += 0x7FFF + ((u >> 16) & 1);   // round-to-nearest-even
    return (short)(u >> 16);
}
__device__ inline float bf2f(ushort_t u) {
    unsigned x = ((unsigned)u) << 16;
    return __builtin_bit_cast(float, x);
}
// packs {lo16: bf16(a), hi16: bf16(b)}
__device__ __forceinline__ unsigned cvtpk(float a, float b) {
    unsigned r;
    asm("v_cvt_pk_bf16_f32 %0, %1, %2" : "=v"(r) : "v"(a), "v"(b));
    return r;
}

__device__ __forceinline__ void gload16(const void* g, void* l) {
    __builtin_amdgcn_global_load_lds(
        (const __attribute__((address_space(1))) unsigned int*)g,
        (__attribute__((address_space(3))) unsigned int*)l,
        16, 0, 0);
}

// ============ front: bias_mfma (blocks 0..4095) + prep (blocks 4096..5956) ============
struct FrontArgs {
    const float* wsrc0; const float* wsrc1; const float* wsrc2; const float* wsrc3;
    const float* wsrc4; const float* wsrc5; const float* wsrc6; const float* wsrc7;
    ushort_t* wdst0; ushort_t* wdst1; ushort_t* wdst2; ushort_t* wdst3;
    ushort_t* wdst4; ushort_t* wdst5; ushort_t* wdst6; ushort_t* wdst7;
    const float* s; ushort_t* sbf;
    const float* bq; const float* bkv; const float* bqp; const float* bkvp;
    float* biasp;
    const float* p; const float* w_b; const float* b_b; ushort_t* bias_b;
};

__global__ __launch_bounds__(256) void front_kernel(FrontArgs a)
{
    __shared__ __align__(16) char SM[36864];
    const int b = blockIdx.x;
    const int t = threadIdx.x;
    if (b < 4096) {
        float* Pf = (float*)SM;                      // 32 KB
        ushort_t* Wbs = (ushort_t*)(SM + 32768);     // 4 KB
        const int w = t >> 6;
        const size_t row0 = (size_t)b * 64;

        for (int idx = t; idx < 2048; idx += 256) {
            int h = idx >> 7, c = idx & 127;
            float v = (h < 12) ? a.w_b[c * 12 + h] : 0.f;
            int byte = h * 256 + ((c * 2) ^ ((h & 7) << 4));
            *(ushort_t*)((char*)Wbs + byte) = (ushort_t)f2bf(v);
        }
        #pragma unroll
        for (int k = 0; k < 8; ++k) {
            int s2 = k * 256 + t;
            int row = s2 >> 5, ch = s2 & 31;
            const char* src = (const char*)(a.p + (row0 + row) * 128) + ((ch ^ (row & 7)) * 16);
            gload16(src, (char*)Pf + (size_t)(k * 256 + w * 64) * 16);
        }
        __syncthreads();

        const int l = t & 63, lr = l & 15, hk = l >> 4;
        const int jb = w * 16;
        f32x4 acc = (f32x4){0.f, 0.f, 0.f, 0.f};
        #pragma unroll
        for (int ks = 0; ks < 4; ++ks) {
            int row = jb + lr;
            int kc = ks * 8 + hk * 2;
            const char* base = (const char*)Pf + row * 512;
            f32x4 v0 = *(const f32x4*)(base + ((kc ^ (row & 7)) * 16));
            f32x4 v1 = *(const f32x4*)(base + (((kc + 1) ^ (row & 7)) * 16));
            bf16x8 afr;
            afr[0] = f2bf(v0[0]); afr[1] = f2bf(v0[1]); afr[2] = f2bf(v0[2]); afr[3] = f2bf(v0[3]);
            afr[4] = f2bf(v1[0]); afr[5] = f2bf(v1[1]); afr[6] = f2bf(v1[2]); afr[7] = f2bf(v1[3]);
            bf16x8 bfr = *(const bf16x8*)((char*)Wbs + lr * 256 +
                            ((ks * 64 + hk * 16) ^ ((lr & 7) << 4)));
            acc = __builtin_amdgcn_mfma_f32_16x16x32_bf16(afr, bfr, acc, 0, 0, 0);
        }
        if (lr < 12) {
            float bb = a.b_b[lr];
            size_t gj = row0 + jb + hk * 4;
            sh4 o;
            #pragma unroll
            for (int r = 0; r < 4; ++r) o[r] = f2bf(SC_B * (acc[r] + bb));
            *(sh4*)(a.bias_b + (size_t)lr * NN + gj) = o;
        }
    } else {
        const int bp = b - 4096;
        if (bp < 1668) {
            const float* src; ushort_t* dst; int begin, nx, Nc, K;
            if      (bp < 72)   { src=a.wsrc0; dst=a.wdst0; begin=0;    nx=6;  Nc=192; K=384; }
            else if (bp < 216)  { src=a.wsrc1; dst=a.wdst1; begin=72;   nx=12; Nc=384; K=384; }
            else if (bp < 276)  { src=a.wsrc2; dst=a.wdst2; begin=216;  nx=5;  Nc=144; K=384; }
            else if (bp < 444)  { src=a.wsrc3; dst=a.wdst3; begin=276;  nx=14; Nc=432; K=384; }
            else if (bp < 1236) { src=a.wsrc4; dst=a.wdst4; begin=444;  nx=12; Nc=384; K=2112; }
            else if (bp < 1380) { src=a.wsrc5; dst=a.wdst5; begin=1236; nx=12; Nc=384; K=384; }
            else if (bp < 1524) { src=a.wsrc6; dst=a.wdst6; begin=1380; nx=12; Nc=384; K=384; }
            else                { src=a.wsrc7; dst=a.wdst7; begin=1524; nx=12; Nc=384; K=384; }
            int lb = bp - begin;
            int cx = (lb % nx) * 32, ky = (lb / nx) * 32;
            float (*tile)[33] = (float(*)[33])SM;
            const int tx = t & 31, ty = t >> 5;
            for (int r = ty; r < 32; r += 8) {
                int c = cx + tx;
                tile[r][tx] = (c < Nc) ? src[(size_t)(ky + r) * Nc + c] : 0.f;
            }
            __syncthreads();
            for (int r = ty; r < 32; r += 8) {
                int orow = cx + r;
                if (orow < Nc)
                    dst[(size_t)orow * K + ky + tx] = (ushort_t)f2bf(tile[tx][r]);
            }
        } else if (bp < 1860) {
            int i4 = (bp - 1668) * 256 + t;
            f32x4 v = *(const f32x4*)(a.s + (size_t)i4 * 4);
            sh4 o;
            o[0] = f2bf(v[0]); o[1] = f2bf(v[1]); o[2] = f2bf(v[2]); o[3] = f2bf(v[3]);
            *(sh4*)(a.sbf + (size_t)i4 * 4) = o;
        } else {
            for (int idx = t; idx < 1152; idx += 256) {
                float v;
                if (idx < 192)      v = a.bq[idx];
                else if (idx < 576) v = a.bkv[idx - 192];
                else if (idx < 720) v = a.bqp[idx - 576];
                else                v = a.bkvp[idx - 720];
                a.biasp[idx] = v;
            }
        }
    }
}

// ============ bf16 MFMA GEMM, 64x64 tile, BK=32, 2-phase pipelined, split-K ============
__global__ __launch_bounds__(256) void gemm_bf16(
    const ushort_t* __restrict__ A, const ushort_t* __restrict__ Bt,
    float* __restrict__ part, int K, int KOUT, int nk)
{
    __shared__ __align__(16) ushort_t As[2][2048];
    __shared__ __align__(16) ushort_t Bs[2][2048];
    const int t = threadIdx.x, w = t >> 6, l = t & 63;
    const int i0 = blockIdx.x * 64, n0 = blockIdx.y * 64, sp = blockIdx.z;
    const int kbase = sp * nk * 32;

    const int srow = w * 16 + (l >> 2);
    const int skb = (l & 3) ^ ((srow >> 1) & 3);
    const ushort_t* aSrc = A + (size_t)(i0 + srow) * K + kbase + skb * 8;
    const ushort_t* bSrc = Bt + (size_t)(n0 + srow) * K + kbase + skb * 8;
    ushort_t* aDst = &As[0][0] + w * 512;
    ushort_t* bDst = &Bs[0][0] + w * 512;

    const int r0 = (w >> 1) * 32, c0 = (w & 1) * 32, lr = l & 15, hk = l >> 4;
    int aOff[2], bOff[2];
    #pragma unroll
    for (int m = 0; m < 2; ++m) {
        int row = r0 + m * 16 + lr;
        aOff[m] = row * 64 + ((hk ^ ((row >> 1) & 3)) << 4);
    }
    #pragma unroll
    for (int n = 0; n < 2; ++n) {
        int row = c0 + n * 16 + lr;
        bOff[n] = row * 64 + ((hk ^ ((row >> 1) & 3)) << 4);
    }

    f32x4 acc[2][2];
    #pragma unroll
    for (int m = 0; m < 2; ++m)
        #pragma unroll
        for (int n = 0; n < 2; ++n) acc[m][n] = (f32x4){0.f, 0.f, 0.f, 0.f};

    gload16(aSrc, aDst);
    gload16(bSrc, bDst);
    __syncthreads();

    int cur = 0;
    for (int it = 0; it < nk; ++it) {
        if (it + 1 < nk) {
            gload16(aSrc + (it + 1) * 32, aDst + (cur ^ 1) * 2048);
            gload16(bSrc + (it + 1) * 32, bDst + (cur ^ 1) * 2048);
        }
        const char* ab = (const char*)&As[cur][0];
        const char* bb = (const char*)&Bs[cur][0];
        bf16x8 a0 = *(const bf16x8*)(ab + aOff[0]);
        bf16x8 a1 = *(const bf16x8*)(ab + aOff[1]);
        bf16x8 b0 = *(const bf16x8*)(bb + bOff[0]);
        bf16x8 b1 = *(const bf16x8*)(bb + bOff[1]);
        acc[0][0] = __builtin_amdgcn_mfma_f32_16x16x32_bf16(a0, b0, acc[0][0], 0, 0, 0);
        acc[0][1] = __builtin_amdgcn_mfma_f32_16x16x32_bf16(a0, b1, acc[0][1], 0, 0, 0);
        acc[1][0] = __builtin_amdgcn_mfma_f32_16x16x32_bf16(a1, b0, acc[1][0], 0, 0, 0);
        acc[1][1] = __builtin_amdgcn_mfma_f32_16x16x32_bf16(a1, b1, acc[1][1], 0, 0, 0);
        __syncthreads();
        cur ^= 1;
    }

    #pragma unroll
    for (int m = 0; m < 2; ++m)
        #pragma unroll
        for (int n = 0; n < 2; ++n) {
            int col = n0 + c0 + n * 16 + lr;
            int rowb = i0 + r0 + m * 16 + (l >> 4) * 4;
            float* pr = part + ((size_t)sp * 512 + rowb) * KOUT + col;
            #pragma unroll
            for (int j = 0; j < 4; ++j)
                pr[(size_t)j * KOUT] = acc[m][n][j];
        }
}

// ============ gemm_red: A = relu(sum of 3 partials + kbias), K=384; B via gload16 ==========
__global__ __launch_bounds__(256) void gemm_red(
    const float* __restrict__ partsIn, const float* __restrict__ kbias,
    const ushort_t* __restrict__ Bt, float* __restrict__ partOut, int nk)
{
    __shared__ __align__(16) ushort_t As[2][2048];
    __shared__ __align__(16) ushort_t Bs[2][2048];
    const int t = threadIdx.x, w = t >> 6, l = t & 63;
    const int i0 = blockIdx.x * 64, n0 = blockIdx.y * 64, sp = blockIdx.z;
    const int kbase = sp * nk * 32;

    const int srow = w * 16 + (l >> 2);
    const int skb = (l & 3) ^ ((srow >> 1) & 3);
    const ushort_t* bSrc = Bt + (size_t)(n0 + srow) * 384 + kbase + skb * 8;
    ushort_t* bDst = &Bs[0][0] + w * 512;

    const int ar = t >> 2, apch = t & 3;
    const int agch = apch ^ ((ar >> 1) & 3);
    const float* aBase = partsIn + (size_t)(i0 + ar) * 384 + kbase + agch * 8;
    const int aByte = ar * 64 + apch * 16;

    const int r0 = (w >> 1) * 32, c0 = (w & 1) * 32, lr = l & 15, hk = l >> 4;
    int aOff[2], bOff[2];
    #pragma unroll
    for (int m = 0; m < 2; ++m) {
        int row = r0 + m * 16 + lr;
        aOff[m] = row * 64 + ((hk ^ ((row >> 1) & 3)) << 4);
    }
    #pragma unroll
    for (int n = 0; n < 2; ++n) {
        int row = c0 + n * 16 + lr;
        bOff[n] = row * 64 + ((hk ^ ((row >> 1) & 3)) << 4);
    }

    f32x4 av0, av1;
    #define A_LOAD(it)                                                            \
        {                                                                         \
            const float* ap = aBase + (it) * 32;                                  \
            av0 = *(const f32x4*)(ap) + *(const f32x4*)(ap + 196608)              \
                + *(const f32x4*)(ap + 393216);                                   \
            av1 = *(const f32x4*)(ap + 4) + *(const f32x4*)(ap + 196608 + 4)      \
                + *(const f32x4*)(ap + 393216 + 4);                               \
        }
    #define A_STORE(buf, it)                                                      \
        {                                                                         \
            int kk = kbase + (it) * 32 + agch * 8;                                \
            f32x4 kb0 = *(const f32x4*)(kbias + kk);                              \
            f32x4 kb1 = *(const f32x4*)(kbias + kk + 4);                          \
            f32x4 s0 = av0 + kb0, s1 = av1 + kb1;                                 \
            u32x4 pk;                                                             \
            pk[0] = cvtpk(fmaxf(s0[0], 0.f), fmaxf(s0[1], 0.f));                  \
            pk[1] = cvtpk(fmaxf(s0[2], 0.f), fmaxf(s0[3], 0.f));                  \
            pk[2] = cvtpk(fmaxf(s1[0], 0.f), fmaxf(s1[1], 0.f));                  \
            pk[3] = cvtpk(fmaxf(s1[2], 0.f), fmaxf(s1[3], 0.f));                  \
            *(u32x4*)((char*)&As[buf][0] + aByte) = pk;                           \
        }

    f32x4 acc[2][2];
    #pragma unroll
    for (int m = 0; m < 2; ++m)
        #pragma unroll
        for (int n = 0; n < 2; ++n) acc[m][n] = (f32x4){0.f, 0.f, 0.f, 0.f};

    gload16(bSrc, bDst);
    A_LOAD(0);
    A_STORE(0, 0);
    __syncthreads();

    int cur = 0;
    for (int it = 0; it < nk; ++it) {
        if (it + 1 < nk) {
            gload16(bSrc + (it + 1) * 32, bDst + (cur ^ 1) * 2048);
            A_LOAD(it + 1);
        }
        const char* ab = (const char*)&As[cur][0];
        const char* bb = (const char*)&Bs[cur][0];
        bf16x8 a0 = *(const bf16x8*)(ab + aOff[0]);
        bf16x8 a1 = *(const bf16x8*)(ab + aOff[1]);
        bf16x8 b0 = *(const bf16x8*)(bb + bOff[0]);
        bf16x8 b1 = *(const bf16x8*)(bb + bOff[1]);
        acc[0][0] = __builtin_amdgcn_mfma_f32_16x16x32_bf16(a0, b0, acc[0][0], 0, 0, 0);
        acc[0][1] = __builtin_amdgcn_mfma_f32_16x16x32_bf16(a0, b1, acc[0][1], 0, 0, 0);
        acc[1][0] = __builtin_amdgcn_mfma_f32_16x16x32_bf16(a1, b0, acc[1][0], 0, 0, 0);
        acc[1][1] = __builtin_amdgcn_mfma_f32_16x16x32_bf16(a1, b1, acc[1][1], 0, 0, 0);
        if (it + 1 < nk) A_STORE(cur ^ 1, it + 1);
        __syncthreads();
        cur ^= 1;
    }
    #undef A_LOAD
    #undef A_STORE

    #pragma unroll
    for (int m = 0; m < 2; ++m)
        #pragma unroll
        for (int n = 0; n < 2; ++n) {
            int col = n0 + c0 + n * 16 + lr;
            int rowb = i0 + r0 + m * 16 + (l >> 4) * 4;
            float* pr = partOut + ((size_t)sp * 512 + rowb) * 384 + col;
            #pragma unroll
            for (int j = 0; j < 4; ++j)
                pr[(size_t)j * 384] = acc[m][n][j];
        }
}

// ============ fused reduce split-K + bias + resid + LayerNorm (+ optional rigid update) ====
__global__ void reduce_ln(const float* __restrict__ parts, int S,
                          const float* __restrict__ gbias, const float* __restrict__ resid,
                          const float* __restrict__ g, const float* __restrict__ b,
                          float* __restrict__ outf, ushort_t* __restrict__ outbf,
                          const float* __restrict__ bb_w, const float* __restrict__ bb_b,
                          const float* __restrict__ rot, const float* __restrict__ trans,
                          float* __restrict__ out_rot, float* __restrict__ out_trans)
{
    __shared__ float buf[384];
    __shared__ float red[2], red2[2];
    __shared__ float ush[2][6];
    const int i = blockIdx.x, t = threadIdx.x;  // 128 threads
    float s = 0.f, sq = 0.f;
    for (int k = t; k < 384; k += 128) {
        float v = gbias[k] + resid[(size_t)i * 384 + k];
        for (int s2 = 0; s2 < S; ++s2)
            v += parts[((size_t)s2 * 512 + i) * 384 + k];
        buf[k] = v; s += v; sq += v * v;
    }
    for (int off = 32; off; off >>= 1) { s += __shfl_xor(s, off); sq += __shfl_xor(sq, off); }
    if ((t & 63) == 0) { red[t >> 6] = s; red2[t >> 6] = sq; }
    __syncthreads();
    float mean = (red[0] + red[1]) * (1.0f / 384.0f);
    float var = (red2[0] + red2[1]) * (1.0f / 384.0f) - mean * mean;
    float rstd = rsqrtf(var + 1e-5f);
    float onorm[3];
    #pragma unroll
    for (int kk = 0; kk < 3; ++kk) {
        int k = t + kk * 128;
        float o = (buf[k] - mean) * rstd * g[k] + b[k];
        onorm[kk] = o;
        if (outf) outf[(size_t)i * 384 + k] = o;
        if (outbf) outbf[(size_t)i * 384 + k] = (ushort_t)f2bf(o);
    }
    if (!bb_w) return;
    float u[6] = {0.f, 0.f, 0.f, 0.f, 0.f, 0.f};
    #pragma unroll
    for (int kk = 0; kk < 3; ++kk) {
        int k = t + kk * 128;
        float sv = onorm[kk];
        #pragma unroll
        for (int c = 0; c < 6; ++c) u[c] += sv * bb_w[k * 6 + c];
    }
    #pragma unroll
    for (int c = 0; c < 6; ++c)
        for (int off = 32; off; off >>= 1) u[c] += __shfl_xor(u[c], off);
    if ((t & 63) == 0) {
        #pragma unroll
        for (int c = 0; c < 6; ++c) ush[t >> 6][c] = u[c];
    }
    __syncthreads();
    if (t == 0) {
        float uu[6];
        #pragma unroll
        for (int c = 0; c < 6; ++c) uu[c] = ush[0][c] + ush[1][c] + bb_b[c];
        float inq = rsqrtf(1.0f + uu[0]*uu[0] + uu[1]*uu[1] + uu[2]*uu[2]);
        float w = inq, x = uu[0]*inq, y = uu[1]*inq, z = uu[2]*inq;
        float Ru[9];
        Ru[0] = 1.f - 2.f*(y*y + z*z); Ru[1] = 2.f*(x*y - w*z); Ru[2] = 2.f*(x*z + w*y);
        Ru[3] = 2.f*(x*y + w*z); Ru[4] = 1.f - 2.f*(x*x + z*z); Ru[5] = 2.f*(y*z - w*x);
        Ru[6] = 2.f*(x*z - w*y); Ru[7] = 2.f*(y*z + w*x); Ru[8] = 1.f - 2.f*(x*x + y*y);
        const float* R = rot + i * 9;
        #pragma unroll
        for (int a = 0; a < 3; ++a) {
            #pragma unroll
            for (int cc = 0; cc < 3; ++cc)
                out_rot[i * 9 + a * 3 + cc] =
                    R[a*3+0]*Ru[0+cc] + R[a*3+1]*Ru[3+cc] + R[a*3+2]*Ru[6+cc];
            out_trans[i * 3 + a] = R[a*3+0]*uu[3] + R[a*3+1]*uu[4] + R[a*3+2]*uu[5]
                                   + trans[i * 3 + a];
        }
    }
}

// ============ postproj: reduce proj partials + rotate points + emit Qext/Kext/Vext ========
__global__ __launch_bounds__(256) void postproj_kernel(
    const float* __restrict__ parts, const float* __restrict__ biasp,
    const float* __restrict__ rot, const float* __restrict__ trans,
    const float* __restrict__ head_w, const float* __restrict__ mask,
    ushort_t* __restrict__ Qext, ushort_t* __restrict__ Kext, ushort_t* __restrict__ Vext)
{
    __shared__ float buf[1152];
    __shared__ float hwv[12], kc28[12];
    const int j = blockIdx.x, t = threadIdx.x;
    for (int c = t; c < 1152; c += 256)
        buf[c] = biasp[c] + parts[(size_t)j * 1152 + c] + parts[(size_t)(512 + j) * 1152 + c];
    if (t >= 192 && t < 204) {
        int h = t - 192;
        hwv[h] = HW_SC * log1pf(expf(head_w[h]));
    }
    __syncthreads();
    if (t < 192) {
        int base = 576 + t * 3;
        const float* R = rot + j * 9;
        const float* T = trans + j * 3;
        float x = buf[base], y = buf[base + 1], z = buf[base + 2];
        float nx = R[0]*x + R[1]*y + R[2]*z + T[0];
        float ny = R[3]*x + R[4]*y + R[5]*z + T[1];
        float nz = R[6]*x + R[7]*y + R[8]*z + T[2];
        buf[base] = nx; buf[base + 1] = ny; buf[base + 2] = nz;
    }
    __syncthreads();
    if (t < 12) {
        float s2 = 0.f;
        #pragma unroll
        for (int e = 0; e < 12; ++e) { float v = buf[720 + t * 36 + e]; s2 += v * v; }
        kc28[t] = -0.5f * hwv[t] * s2 + (mask[j] - 1.0f) * INFV;
    }
    __syncthreads();
    if (t < 192) {
        int h = t >> 4, c0 = (t & 15) * 2;
        float hwf = hwv[h];
        #pragma unroll
        for (int e = 0; e < 2; ++e) {
            int c = c0 + e;
            float qv, kv2;
            if (c < 16)      { qv = SC_QK * buf[h * 16 + c];           kv2 = buf[192 + h * 32 + c]; }
            else if (c < 28) { qv = hwf * buf[576 + h * 12 + (c - 16)]; kv2 = buf[720 + h * 36 + (c - 16)]; }
            else if (c == 28){ qv = 1.f;                               kv2 = kc28[h]; }
            else             { qv = 0.f;                               kv2 = 0.f; }
            Qext[(size_t)h * 16384 + j * 32 + c] = (ushort_t)f2bf(qv);
            Kext[(size_t)h * 16384 + j * 32 + c] = (ushort_t)f2bf(kv2);
        }
    }
    for (int idx = t; idx < 576; idx += 256) {
        int h = idx / 48, c = idx % 48;
        float v;
        if (c < 16)      v = buf[192 + h * 32 + 16 + c];
        else if (c < 40) v = buf[720 + h * 36 + 12 + (c - 16)];
        else             v = 0.f;
        Vext[(size_t)h * 24576 + c * 512 + j] = (ushort_t)f2bf(v);
    }
}

// ============ attn logits via MFMA + softmax + fused A@V + op finalize ============
__global__ __launch_bounds__(256) void attn_mfma(
    const ushort_t* __restrict__ Qext, const ushort_t* __restrict__ Kext,
    const ushort_t* __restrict__ bias_b, const ushort_t* __restrict__ Vext,
    const float* __restrict__ rot, const float* __restrict__ trans,
    ushort_t* __restrict__ attn_b, ushort_t* __restrict__ catb)
{
    __shared__ float sc[16 * 516];
    __shared__ float redm[64];
    __shared__ float invr[16];
    __shared__ float opl[16][25];
    const int t = threadIdx.x, w = t >> 6, l = t & 63;
    const int i0 = blockIdx.x * 16, h = blockIdx.y;
    const int lr = l & 15, hk = l >> 4;

    #pragma unroll
    for (int it = 0; it < 8; ++it) {
        int elem = (t + it * 256) * 4;
        int i = elem >> 9, j = elem & 511;
        sh4 raw = *(const sh4*)(bias_b + (size_t)h * NN + (size_t)(i0 + i) * 512 + j);
        f32x4 v;
        v[0] = bf2f((ushort_t)raw[0]); v[1] = bf2f((ushort_t)raw[1]);
        v[2] = bf2f((ushort_t)raw[2]); v[3] = bf2f((ushort_t)raw[3]);
        *(f32x4*)(sc + i * 516 + j) = v;
    }
    __syncthreads();

    bf16x8 a0 = *(const bf16x8*)(Qext + (size_t)h * 16384 + (i0 + lr) * 32 + hk * 8);
    f32x4 acc[8];
    #pragma unroll
    for (int n = 0; n < 8; ++n) {
        bf16x8 b = *(const bf16x8*)(Kext + (size_t)h * 16384 +
                                    (w * 128 + n * 16 + lr) * 32 + hk * 8);
        acc[n] = __builtin_amdgcn_mfma_f32_16x16x32_bf16(a0, b, (f32x4){0.f,0.f,0.f,0.f}, 0, 0, 0);
    }

    float rmax[4] = {-3.0e38f, -3.0e38f, -3.0e38f, -3.0e38f};
    #pragma unroll
    for (int n = 0; n < 8; ++n) {
        int col = w * 128 + n * 16 + lr;
        #pragma unroll
        for (int r = 0; r < 4; ++r) {
            int row = hk * 4 + r;
            float v = acc[n][r] + sc[row * 516 + col];
            sc[row * 516 + col] = v;
            rmax[r] = fmaxf(rmax[r], v);
        }
    }
    #pragma unroll
    for (int r = 0; r < 4; ++r) {
        float v = rmax[r];
        v = fmaxf(v, __shfl_xor(v, 1));
        v = fmaxf(v, __shfl_xor(v, 2));
        v = fmaxf(v, __shfl_xor(v, 4));
        v = fmaxf(v, __shfl_xor(v, 8));
        if (lr == 0) redm[w * 16 + hk * 4 + r] = v;
    }
    __syncthreads();

    {
        int row = t >> 4, g = t & 15;
        float mx = fmaxf(fmaxf(redm[row], redm[16 + row]),
                         fmaxf(redm[32 + row], redm[48 + row]));
        float sum = 0.f;
        float* sr = sc + row * 516;
        for (int c = g; c < 512; c += 16) {
            float e = expf(sr[c] - mx);
            sr[c] = e;
            sum += e;
        }
        sum += __shfl_xor(sum, 1);
        sum += __shfl_xor(sum, 2);
        sum += __shfl_xor(sum, 4);
        sum += __shfl_xor(sum, 8);
        if (g == 0) invr[row] = 1.0f / sum;
    }
    __syncthreads();

    #pragma unroll
    for (int it = 0; it < 8; ++it) {
        int elem = (t + it * 256) * 4;
        int i = elem >> 9, j = elem & 511;
        f32x4 v = *(const f32x4*)(sc + i * 516 + j);
        float iv = invr[i];
        sh4 o;
        o[0] = f2bf(v[0] * iv); o[1] = f2bf(v[1] * iv);
        o[2] = f2bf(v[2] * iv); o[3] = f2bf(v[3] * iv);
        *(sh4*)(attn_b + (size_t)h * NN + (size_t)(i0 + i) * 512 + j) = o;
    }

    f32x4 acc3[3];
    acc3[0] = (f32x4){0.f,0.f,0.f,0.f};
    acc3[1] = (f32x4){0.f,0.f,0.f,0.f};
    acc3[2] = (f32x4){0.f,0.f,0.f,0.f};
    const ushort_t* vbase = Vext + (size_t)h * 24576 + lr * 512 + hk * 8;
    #pragma unroll
    for (int kt = 0; kt < 16; ++kt) {
        const float* srow = sc + lr * 516 + kt * 32 + hk * 8;
        f32x4 x0 = *(const f32x4*)(srow);
        f32x4 x1 = *(const f32x4*)(srow + 4);
        u32x4 ap;
        ap[0] = cvtpk(x0[0], x0[1]); ap[1] = cvtpk(x0[2], x0[3]);
        ap[2] = cvtpk(x1[0], x1[1]); ap[3] = cvtpk(x1[2], x1[3]);
        bf16x8 af = __builtin_bit_cast(bf16x8, ap);
        #pragma unroll
        for (int n = 0; n < 3; ++n) {
            bf16x8 bf = *(const bf16x8*)(vbase + n * 16 * 512 + kt * 32);
            acc3[n] = __builtin_amdgcn_mfma_f32_16x16x32_bf16(af, bf, acc3[n], 0, 0, 0);
        }
    }
    #pragma unroll
    for (int n = 0; n < 3; ++n) {
        int c = n * 16 + lr;
        #pragma unroll
        for (int r = 0; r < 4; ++r) {
            int ri = hk * 4 + r;
            float val = acc3[n][r] * invr[ri];
            if (c < 16)
                catb[(size_t)(i0 + ri) * DCAT + h * 16 + c] = (ushort_t)f2bf(val);
            else if (c < 40)
                opl[ri][c - 16] = val;
        }
    }
    __syncthreads();
    if (t < 128) {
        int i16 = t >> 3, pv = t & 7;
        int i = i0 + i16;
        const float* T = trans + i * 3;
        const float* R = rot + i * 9;
        float x = opl[i16][pv * 3 + 0] - T[0];
        float y = opl[i16][pv * 3 + 1] - T[1];
        float z = opl[i16][pv * 3 + 2] - T[2];
        float rx = R[0] * x + R[3] * y + R[6] * z;
        float ry = R[1] * x + R[4] * y + R[7] * z;
        float rz = R[2] * x + R[5] * y + R[8] * z;
        float nm = sqrtf(rx * rx + ry * ry + rz * rz + 1e-8f);
        ushort_t* cr = catb + (size_t)i * DCAT;
        cr[192 + h * 24 + pv * 3 + 0] = (ushort_t)f2bf(rx);
        cr[192 + h * 24 + pv * 3 + 1] = (ushort_t)f2bf(ry);
        cr[192 + h * 24 + pv * 3 + 2] = (ushort_t)f2bf(rz);
        cr[480 + h * 8 + pv] = (ushort_t)f2bf(nm);
    }
}

// ============ o_pair via MFMA from f32 p (L3-warm) ============
__global__ __launch_bounds__(256) void opair_mfma(
    const ushort_t* __restrict__ attn_b, const float* __restrict__ p,
    ushort_t* __restrict__ catb)
{
    __shared__ __align__(16) ushort_t As2[16 * 512];     // 16 KB
    __shared__ __align__(16) ushort_t Pt[2][128 * 72];   // 2 x 18 KB
    const int t = threadIdx.x, i = blockIdx.x;
    const int w = t >> 6, l = t & 63;
    const int lr = l & 15, hk = l >> 4;

    #pragma unroll
    for (int ii = 0; ii < 4; ++ii) {
        int idx = (t + ii * 256) * 8;
        int h = idx >> 9, j = idx & 511;
        bf16x8 v;
        if (h < 12) v = *(const bf16x8*)(attn_b + (size_t)h * NN + (size_t)i * 512 + j);
        else        v = (bf16x8){0,0,0,0,0,0,0,0};
        *(bf16x8*)((char*)As2 + h * 1024 + ((j * 2) ^ ((h & 7) << 4))) = v;
    }

    const int jA = (t >> 3) * 2;
    const int c0 = (t & 7) * 16;
    const float* psrc = p + (size_t)i * 65536;

    f32x4 va[4], vb[4];
    #pragma unroll
    for (int q = 0; q < 4; ++q) {
        va[q] = *(const f32x4*)(psrc + (size_t)jA * 128 + c0 + q * 4);
        vb[q] = *(const f32x4*)(psrc + (size_t)(jA + 1) * 128 + c0 + q * 4);
    }

    #define PACK_TILE(buf)                                                       \
        {                                                                        \
            ushort_t* ptw = &Pt[buf][0];                                         \
            _Pragma("unroll")                                                    \
            for (int e = 0; e < 16; ++e) {                                       \
                int c = c0 + e;                                                  \
                unsigned pk = cvtpk(va[e >> 2][e & 3], vb[e >> 2][e & 3]);       \
                int byte = c * 144 + ((jA * 2) ^ (((c >> 4) & 7) << 4));         \
                *(unsigned*)((char*)ptw + byte) = pk;                            \
            }                                                                    \
        }
    #define LOAD_TILE(tile)                                                      \
        {                                                                        \
            const float* s0 = psrc + (size_t)((tile) * 64 + jA) * 128 + c0;      \
            _Pragma("unroll")                                                    \
            for (int q = 0; q < 4; ++q) {                                        \
                va[q] = *(const f32x4*)(s0 + q * 4);                             \
                vb[q] = *(const f32x4*)(s0 + 128 + q * 4);                       \
            }                                                                    \
        }

    PACK_TILE(0);
    LOAD_TILE(1);

    f32x4 acc[2];
    acc[0] = (f32x4){0.f, 0.f, 0.f, 0.f};
    acc[1] = (f32x4){0.f, 0.f, 0.f, 0.f};

    int cur = 0;
    for (int tile = 0; tile < 8; ++tile) {
        __syncthreads();
        const char* pt = (const char*)&Pt[cur][0];
        #pragma unroll
        for (int ks = 0; ks < 2; ++ks) {
            bf16x8 afr = *(const bf16x8*)((char*)As2 + lr * 1024 +
                            ((tile * 128 + ks * 64 + hk * 16) ^ ((lr & 7) << 4)));
            #pragma unroll
            for (int n = 0; n < 2; ++n) {
                int c = w * 32 + n * 16 + lr;
                bf16x8 bfr = *(const bf16x8*)(pt + c * 144 +
                                ((ks * 64 + hk * 16) ^ (((c >> 4) & 7) << 4)));
                acc[n] = __builtin_amdgcn_mfma_f32_16x16x32_bf16(afr, bfr, acc[n], 0, 0, 0);
            }
        }
        if (tile < 7) {
            PACK_TILE(cur ^ 1);
            if (tile < 6) LOAD_TILE(tile + 2);
            cur ^= 1;
        }
    }
    #undef PACK_TILE
    #undef LOAD_TILE
    #pragma unroll
    for (int n = 0; n < 2; ++n) {
        int c = w * 32 + n * 16 + lr;
        #pragma unroll
        for (int r = 0; r < 4; ++r) {
            int h = hk * 4 + r;
            if (h < 12)
                catb[(size_t)i * DCAT + 576 + h * 128 + c] = (ushort_t)f2bf(acc[n][r]);
        }
    }
}

extern "C" void kernel_launch(void* const* d_in, const int* in_sizes, int n_in,
                              void* d_out, int out_size, void* d_ws, size_t ws_size,
                              hipStream_t stream)
{
    const float* s      = (const float*)d_in[0];
    const float* p      = (const float*)d_in[1];
    const float* rot    = (const float*)d_in[2];
    const float* trans  = (const float*)d_in[3];
    const float* mask   = (const float*)d_in[4];
    const float* w_q    = (const float*)d_in[5];
    const float* b_q    = (const float*)d_in[6];
    const float* w_kv   = (const float*)d_in[7];
    const float* b_kv   = (const float*)d_in[8];
    const float* w_qp   = (const float*)d_in[9];
    const float* b_qp   = (const float*)d_in[10];
    const float* w_kvp  = (const float*)d_in[11];
    const float* b_kvp  = (const float*)d_in[12];
    const float* w_b    = (const float*)d_in[13];
    const float* b_b    = (const float*)d_in[14];
    const float* head_w = (const float*)d_in[15];
    const float* w_o    = (const float*)d_in[16];
    const float* b_o    = (const float*)d_in[17];
    const float* ln1_g  = (const float*)d_in[18];
    const float* ln1_b  = (const float*)d_in[19];
    const float* tw1    = (const float*)d_in[20];
    const float* tb1    = (const float*)d_in[21];
    const float* tw2    = (const float*)d_in[22];
    const float* tb2    = (const float*)d_in[23];
    const float* tw3    = (const float*)d_in[24];
    const float* tb3    = (const float*)d_in[25];
    const float* ln2_g  = (const float*)d_in[26];
    const float* ln2_b  = (const float*)d_in[27];
    const float* bb_w   = (const float*)d_in[28];
    const float* bb_b   = (const float*)d_in[29];

    float* ws = (float*)d_ws;
    float*    parts  = ws;                       // 1179648
    float*    partsB = parts + 589824;           // gemm_red ping-pong
    float*    s1     = parts + 1179648;          // 196608
    float*    biasp  = s1 + 196608;              // 1152
    ushort_t* ub     = (ushort_t*)(biasp + 1152);
    ushort_t* bias_b = ub;                       // 3145728
    ushort_t* attn_b = bias_b + 3145728;         // 3145728
    ushort_t* catb   = attn_b + 3145728;         // 1081344
    ushort_t* sbf    = catb + 1081344;           // 196608
    ushort_t* s1bf   = sbf + 196608;
    ushort_t* h1bf   = s1bf + 196608;            // (spare)
    ushort_t* h2bf   = h1bf + 196608;            // (spare)
    ushort_t* Qext   = h2bf + 196608;            // 196608
    ushort_t* Kext   = Qext + 196608;            // 196608
    ushort_t* Vext   = Kext + 196608;            // 294912
    ushort_t* Wtp    = Vext + 294912;            // 442368
    ushort_t* Wto    = Wtp + 442368;             // 811008
    ushort_t* Wt1    = Wto + 811008;             // 147456
    ushort_t* Wt2    = Wt1 + 147456;
    ushort_t* Wt3    = Wt2 + 147456;

    float* out_s     = (float*)d_out;
    float* out_rot   = out_s + 196608;
    float* out_trans = out_rot + 4608;

    // ---- merged front: bias_mfma (4096 blocks) + prep (1861 blocks) ----
    FrontArgs fa;
    fa.wsrc0 = w_q;  fa.wdst0 = Wtp;
    fa.wsrc1 = w_kv; fa.wdst1 = Wtp + (size_t)192 * 384;
    fa.wsrc2 = w_qp; fa.wdst2 = Wtp + (size_t)576 * 384;
    fa.wsrc3 = w_kvp; fa.wdst3 = Wtp + (size_t)720 * 384;
    fa.wsrc4 = w_o;  fa.wdst4 = Wto;
    fa.wsrc5 = tw1;  fa.wdst5 = Wt1;
    fa.wsrc6 = tw2;  fa.wdst6 = Wt2;
    fa.wsrc7 = tw3;  fa.wdst7 = Wt3;
    fa.s = s; fa.sbf = sbf;
    fa.bq = b_q; fa.bkv = b_kv; fa.bqp = b_qp; fa.bkvp = b_kvp;
    fa.biasp = biasp;
    fa.p = p; fa.w_b = w_b; fa.b_b = b_b; fa.bias_b = bias_b;
    front_kernel<<<5957, 256, 0, stream>>>(fa);

    // ---- projection GEMM + fused post-processing ----
    gemm_bf16<<<dim3(8, 18, 2), 256, 0, stream>>>(sbf, Wtp, parts, 384, 1152, 6);
    postproj_kernel<<<512, 256, 0, stream>>>(parts, biasp, rot, trans, head_w, mask,
                                             Qext, Kext, Vext);

    // ---- attention ----
    attn_mfma<<<dim3(32, 12), 256, 0, stream>>>(Qext, Kext, bias_b, Vext, rot, trans,
                                                attn_b, catb);
    opair_mfma<<<512, 256, 0, stream>>>(attn_b, p, catb);

    // ---- output projection + residual + LN1 ----
    gemm_bf16<<<dim3(8, 6, 6), 256, 0, stream>>>(catb, Wto, parts, 2112, 384, 11);
    reduce_ln<<<512, 128, 0, stream>>>(parts, 6, b_o, s, ln1_g, ln1_b, s1, s1bf,
                                       nullptr, nullptr, nullptr, nullptr, nullptr, nullptr);

    // ---- transition: g1 (bf16 path), g2/g3 (fused reduce+relu staging) ----
    gemm_bf16<<<dim3(8, 6, 3), 256, 0, stream>>>(s1bf, Wt1, parts, 384, 384, 4);
    gemm_red<<<dim3(8, 6, 3), 256, 0, stream>>>(parts, tb1, Wt2, partsB, 4);
    gemm_red<<<dim3(8, 6, 3), 256, 0, stream>>>(partsB, tb2, Wt3, parts, 4);
    // LN2 + fused rigid update
    reduce_ln<<<512, 128, 0, stream>>>(parts, 3, tb3, s1, ln2_g, ln2_b, out_s, nullptr,
                                       bb_w, bb_b, rot, trans, out_rot, out_trans);
}

// Round 16
// 105.758 us; speedup vs baseline: 1.1944x; 1.1807x over previous
//
#include <hip/hip_runtime.h>
#include <math.h>

#define N 512
#define CS 384
#define CP 128
#define CH 16
#define NH 12
#define NN (N*N)
#define DCAT 2112
#define INFV 100000.0f

__device__ __constant__ float SC_QK = 0.14433756729740643f; // sqrt(1/48)
#define SC_B  0.57735026918962576f  // sqrt(1/3)
#define HW_SC 0.13608276348795434f  // sqrt(1/54)

typedef __attribute__((ext_vector_type(8))) short bf16x8;
typedef __attribute__((ext_vector_type(4))) float f32x4;
typedef __attribute__((ext_vector_type(4))) short sh4;
typedef __attribute__((ext_vector_type(4))) unsigned u32x4;
typedef unsigned short ushort_t;

__device__ inline short f2bf(float v) {
    unsigned u = __builtin_bit_cast(unsigned, v);
    u += 0x7FFF + ((u >> 16) & 1);   // round-to-nearest-even
    return (short)(u >> 16);
}
__device__ inline float bf2f(ushort_t u) {
    unsigned x = ((unsigned)u) << 16;
    return __builtin_bit_cast(float, x);
}
__device__ __forceinline__ unsigned cvtpk(float a, float b) {
    unsigned r;
    asm("v_cvt_pk_bf16_f32 %0, %1, %2" : "=v"(r) : "v"(a), "v"(b));
    return r;
}

__device__ __forceinline__ void gload16(const void* g, void* l) {
    __builtin_amdgcn_global_load_lds(
        (const __attribute__((address_space(1))) unsigned int*)g,
        (__attribute__((address_space(3))) unsigned int*)l,
        16, 0, 0);
}

// ============ prep: weight transposes + s conversion + bias concat ============
struct PrepArgs {
    const float* wsrc0; const float* wsrc1; const float* wsrc2; const float* wsrc3;
    const float* wsrc4; const float* wsrc5; const float* wsrc6; const float* wsrc7;
    ushort_t* wdst0; ushort_t* wdst1; ushort_t* wdst2; ushort_t* wdst3;
    ushort_t* wdst4; ushort_t* wdst5; ushort_t* wdst6; ushort_t* wdst7;
    const float* s; ushort_t* sbf;
    const float* bq; const float* bkv; const float* bqp; const float* bkvp;
    float* biasp;
};

__global__ __launch_bounds__(256) void prep_kernel(PrepArgs a)
{
    __shared__ float tile[32][33];
    const int bp = blockIdx.x;
    const int t = threadIdx.x;
    if (bp < 1668) {
        const float* src; ushort_t* dst; int begin, nx, Nc, K;
        if      (bp < 72)   { src=a.wsrc0; dst=a.wdst0; begin=0;    nx=6;  Nc=192; K=384; }
        else if (bp < 216)  { src=a.wsrc1; dst=a.wdst1; begin=72;   nx=12; Nc=384; K=384; }
        else if (bp < 276)  { src=a.wsrc2; dst=a.wdst2; begin=216;  nx=5;  Nc=144; K=384; }
        else if (bp < 444)  { src=a.wsrc3; dst=a.wdst3; begin=276;  nx=14; Nc=432; K=384; }
        else if (bp < 1236) { src=a.wsrc4; dst=a.wdst4; begin=444;  nx=12; Nc=384; K=2112; }
        else if (bp < 1380) { src=a.wsrc5; dst=a.wdst5; begin=1236; nx=12; Nc=384; K=384; }
        else if (bp < 1524) { src=a.wsrc6; dst=a.wdst6; begin=1380; nx=12; Nc=384; K=384; }
        else                { src=a.wsrc7; dst=a.wdst7; begin=1524; nx=12; Nc=384; K=384; }
        int lb = bp - begin;
        int cx = (lb % nx) * 32, ky = (lb / nx) * 32;
        const int tx = t & 31, ty = t >> 5;
        for (int r = ty; r < 32; r += 8) {
            int c = cx + tx;
            tile[r][tx] = (c < Nc) ? src[(size_t)(ky + r) * Nc + c] : 0.f;
        }
        __syncthreads();
        for (int r = ty; r < 32; r += 8) {
            int orow = cx + r;
            if (orow < Nc)
                dst[(size_t)orow * K + ky + tx] = (ushort_t)f2bf(tile[tx][r]);
        }
    } else if (bp < 1860) {
        int i4 = (bp - 1668) * 256 + t;
        f32x4 v = *(const f32x4*)(a.s + (size_t)i4 * 4);
        sh4 o;
        o[0] = f2bf(v[0]); o[1] = f2bf(v[1]); o[2] = f2bf(v[2]); o[3] = f2bf(v[3]);
        *(sh4*)(a.sbf + (size_t)i4 * 4) = o;
    } else {
        for (int idx = t; idx < 1152; idx += 256) {
            float v;
            if (idx < 192)      v = a.bq[idx];
            else if (idx < 576) v = a.bkv[idx - 192];
            else if (idx < 720) v = a.bqp[idx - 576];
            else                v = a.bkvp[idx - 720];
            a.biasp[idx] = v;
        }
    }
}

// ============ bf16 MFMA GEMM, 64x64 tile, BK=32, 2-phase pipelined, split-K ============
__global__ __launch_bounds__(256) void gemm_bf16(
    const ushort_t* __restrict__ A, const ushort_t* __restrict__ Bt,
    float* __restrict__ part, int K, int KOUT, int nk)
{
    __shared__ __align__(16) ushort_t As[2][2048];
    __shared__ __align__(16) ushort_t Bs[2][2048];
    const int t = threadIdx.x, w = t >> 6, l = t & 63;
    const int i0 = blockIdx.x * 64, n0 = blockIdx.y * 64, sp = blockIdx.z;
    const int kbase = sp * nk * 32;

    const int srow = w * 16 + (l >> 2);
    const int skb = (l & 3) ^ ((srow >> 1) & 3);
    const ushort_t* aSrc = A + (size_t)(i0 + srow) * K + kbase + skb * 8;
    const ushort_t* bSrc = Bt + (size_t)(n0 + srow) * K + kbase + skb * 8;
    ushort_t* aDst = &As[0][0] + w * 512;
    ushort_t* bDst = &Bs[0][0] + w * 512;

    const int r0 = (w >> 1) * 32, c0 = (w & 1) * 32, lr = l & 15, hk = l >> 4;
    int aOff[2], bOff[2];
    #pragma unroll
    for (int m = 0; m < 2; ++m) {
        int row = r0 + m * 16 + lr;
        aOff[m] = row * 64 + ((hk ^ ((row >> 1) & 3)) << 4);
    }
    #pragma unroll
    for (int n = 0; n < 2; ++n) {
        int row = c0 + n * 16 + lr;
        bOff[n] = row * 64 + ((hk ^ ((row >> 1) & 3)) << 4);
    }

    f32x4 acc[2][2];
    #pragma unroll
    for (int m = 0; m < 2; ++m)
        #pragma unroll
        for (int n = 0; n < 2; ++n) acc[m][n] = (f32x4){0.f, 0.f, 0.f, 0.f};

    gload16(aSrc, aDst);
    gload16(bSrc, bDst);
    __syncthreads();

    int cur = 0;
    for (int it = 0; it < nk; ++it) {
        if (it + 1 < nk) {
            gload16(aSrc + (it + 1) * 32, aDst + (cur ^ 1) * 2048);
            gload16(bSrc + (it + 1) * 32, bDst + (cur ^ 1) * 2048);
        }
        const char* ab = (const char*)&As[cur][0];
        const char* bb = (const char*)&Bs[cur][0];
        bf16x8 a0 = *(const bf16x8*)(ab + aOff[0]);
        bf16x8 a1 = *(const bf16x8*)(ab + aOff[1]);
        bf16x8 b0 = *(const bf16x8*)(bb + bOff[0]);
        bf16x8 b1 = *(const bf16x8*)(bb + bOff[1]);
        acc[0][0] = __builtin_amdgcn_mfma_f32_16x16x32_bf16(a0, b0, acc[0][0], 0, 0, 0);
        acc[0][1] = __builtin_amdgcn_mfma_f32_16x16x32_bf16(a0, b1, acc[0][1], 0, 0, 0);
        acc[1][0] = __builtin_amdgcn_mfma_f32_16x16x32_bf16(a1, b0, acc[1][0], 0, 0, 0);
        acc[1][1] = __builtin_amdgcn_mfma_f32_16x16x32_bf16(a1, b1, acc[1][1], 0, 0, 0);
        __syncthreads();
        cur ^= 1;
    }

    #pragma unroll
    for (int m = 0; m < 2; ++m)
        #pragma unroll
        for (int n = 0; n < 2; ++n) {
            int col = n0 + c0 + n * 16 + lr;
            int rowb = i0 + r0 + m * 16 + (l >> 4) * 4;
            float* pr = part + ((size_t)sp * 512 + rowb) * KOUT + col;
            #pragma unroll
            for (int j = 0; j < 4; ++j)
                pr[(size_t)j * KOUT] = acc[m][n][j];
        }
}

// ============ gemm_red: A = relu(sum of 3 partials + kbias), K=384; B via gload16 ==========
__global__ __launch_bounds__(256) void gemm_red(
    const float* __restrict__ partsIn, const float* __restrict__ kbias,
    const ushort_t* __restrict__ Bt, float* __restrict__ partOut, int nk)
{
    __shared__ __align__(16) ushort_t As[2][2048];
    __shared__ __align__(16) ushort_t Bs[2][2048];
    const int t = threadIdx.x, w = t >> 6, l = t & 63;
    const int i0 = blockIdx.x * 64, n0 = blockIdx.y * 64, sp = blockIdx.z;
    const int kbase = sp * nk * 32;

    const int srow = w * 16 + (l >> 2);
    const int skb = (l & 3) ^ ((srow >> 1) & 3);
    const ushort_t* bSrc = Bt + (size_t)(n0 + srow) * 384 + kbase + skb * 8;
    ushort_t* bDst = &Bs[0][0] + w * 512;

    const int ar = t >> 2, apch = t & 3;
    const int agch = apch ^ ((ar >> 1) & 3);
    const float* aBase = partsIn + (size_t)(i0 + ar) * 384 + kbase + agch * 8;
    const int aByte = ar * 64 + apch * 16;

    const int r0 = (w >> 1) * 32, c0 = (w & 1) * 32, lr = l & 15, hk = l >> 4;
    int aOff[2], bOff[2];
    #pragma unroll
    for (int m = 0; m < 2; ++m) {
        int row = r0 + m * 16 + lr;
        aOff[m] = row * 64 + ((hk ^ ((row >> 1) & 3)) << 4);
    }
    #pragma unroll
    for (int n = 0; n < 2; ++n) {
        int row = c0 + n * 16 + lr;
        bOff[n] = row * 64 + ((hk ^ ((row >> 1) & 3)) << 4);
    }

    f32x4 av0, av1;
    #define A_LOAD(it)                                                            \
        {                                                                         \
            const float* ap = aBase + (it) * 32;                                  \
            av0 = *(const f32x4*)(ap) + *(const f32x4*)(ap + 196608)              \
                + *(const f32x4*)(ap + 393216);                                   \
            av1 = *(const f32x4*)(ap + 4) + *(const f32x4*)(ap + 196608 + 4)      \
                + *(const f32x4*)(ap + 393216 + 4);                               \
        }
    #define A_STORE(buf, it)                                                      \
        {                                                                         \
            int kk = kbase + (it) * 32 + agch * 8;                                \
            f32x4 kb0 = *(const f32x4*)(kbias + kk);                              \
            f32x4 kb1 = *(const f32x4*)(kbias + kk + 4);                          \
            f32x4 s0 = av0 + kb0, s1 = av1 + kb1;                                 \
            u32x4 pk;                                                             \
            pk[0] = cvtpk(fmaxf(s0[0], 0.f), fmaxf(s0[1], 0.f));                  \
            pk[1] = cvtpk(fmaxf(s0[2], 0.f), fmaxf(s0[3], 0.f));                  \
            pk[2] = cvtpk(fmaxf(s1[0], 0.f), fmaxf(s1[1], 0.f));                  \
            pk[3] = cvtpk(fmaxf(s1[2], 0.f), fmaxf(s1[3], 0.f));                  \
            *(u32x4*)((char*)&As[buf][0] + aByte) = pk;                           \
        }

    f32x4 acc[2][2];
    #pragma unroll
    for (int m = 0; m < 2; ++m)
        #pragma unroll
        for (int n = 0; n < 2; ++n) acc[m][n] = (f32x4){0.f, 0.f, 0.f, 0.f};

    gload16(bSrc, bDst);
    A_LOAD(0);
    A_STORE(0, 0);
    __syncthreads();

    int cur = 0;
    for (int it = 0; it < nk; ++it) {
        if (it + 1 < nk) {
            gload16(bSrc + (it + 1) * 32, bDst + (cur ^ 1) * 2048);
            A_LOAD(it + 1);
        }
        const char* ab = (const char*)&As[cur][0];
        const char* bb = (const char*)&Bs[cur][0];
        bf16x8 a0 = *(const bf16x8*)(ab + aOff[0]);
        bf16x8 a1 = *(const bf16x8*)(ab + aOff[1]);
        bf16x8 b0 = *(const bf16x8*)(bb + bOff[0]);
        bf16x8 b1 = *(const bf16x8*)(bb + bOff[1]);
        acc[0][0] = __builtin_amdgcn_mfma_f32_16x16x32_bf16(a0, b0, acc[0][0], 0, 0, 0);
        acc[0][1] = __builtin_amdgcn_mfma_f32_16x16x32_bf16(a0, b1, acc[0][1], 0, 0, 0);
        acc[1][0] = __builtin_amdgcn_mfma_f32_16x16x32_bf16(a1, b0, acc[1][0], 0, 0, 0);
        acc[1][1] = __builtin_amdgcn_mfma_f32_16x16x32_bf16(a1, b1, acc[1][1], 0, 0, 0);
        if (it + 1 < nk) A_STORE(cur ^ 1, it + 1);
        __syncthreads();
        cur ^= 1;
    }
    #undef A_LOAD
    #undef A_STORE

    #pragma unroll
    for (int m = 0; m < 2; ++m)
        #pragma unroll
        for (int n = 0; n < 2; ++n) {
            int col = n0 + c0 + n * 16 + lr;
            int rowb = i0 + r0 + m * 16 + (l >> 4) * 4;
            float* pr = partOut + ((size_t)sp * 512 + rowb) * 384 + col;
            #pragma unroll
            for (int j = 0; j < 4; ++j)
                pr[(size_t)j * 384] = acc[m][n][j];
        }
}

// ============ fused reduce split-K + bias + resid + LayerNorm (+ optional rigid update) ====
__global__ void reduce_ln(const float* __restrict__ parts, int S,
                          const float* __restrict__ gbias, const float* __restrict__ resid,
                          const float* __restrict__ g, const float* __restrict__ b,
                          float* __restrict__ outf, ushort_t* __restrict__ outbf,
                          const float* __restrict__ bb_w, const float* __restrict__ bb_b,
                          const float* __restrict__ rot, const float* __restrict__ trans,
                          float* __restrict__ out_rot, float* __restrict__ out_trans)
{
    __shared__ float buf[384];
    __shared__ float red[2], red2[2];
    __shared__ float ush[2][6];
    const int i = blockIdx.x, t = threadIdx.x;  // 128 threads
    float s = 0.f, sq = 0.f;
    for (int k = t; k < 384; k += 128) {
        float v = gbias[k] + resid[(size_t)i * 384 + k];
        for (int s2 = 0; s2 < S; ++s2)
            v += parts[((size_t)s2 * 512 + i) * 384 + k];
        buf[k] = v; s += v; sq += v * v;
    }
    for (int off = 32; off; off >>= 1) { s += __shfl_xor(s, off); sq += __shfl_xor(sq, off); }
    if ((t & 63) == 0) { red[t >> 6] = s; red2[t >> 6] = sq; }
    __syncthreads();
    float mean = (red[0] + red[1]) * (1.0f / 384.0f);
    float var = (red2[0] + red2[1]) * (1.0f / 384.0f) - mean * mean;
    float rstd = rsqrtf(var + 1e-5f);
    float onorm[3];
    #pragma unroll
    for (int kk = 0; kk < 3; ++kk) {
        int k = t + kk * 128;
        float o = (buf[k] - mean) * rstd * g[k] + b[k];
        onorm[kk] = o;
        if (outf) outf[(size_t)i * 384 + k] = o;
        if (outbf) outbf[(size_t)i * 384 + k] = (ushort_t)f2bf(o);
    }
    if (!bb_w) return;
    float u[6] = {0.f, 0.f, 0.f, 0.f, 0.f, 0.f};
    #pragma unroll
    for (int kk = 0; kk < 3; ++kk) {
        int k = t + kk * 128;
        float sv = onorm[kk];
        #pragma unroll
        for (int c = 0; c < 6; ++c) u[c] += sv * bb_w[k * 6 + c];
    }
    #pragma unroll
    for (int c = 0; c < 6; ++c)
        for (int off = 32; off; off >>= 1) u[c] += __shfl_xor(u[c], off);
    if ((t & 63) == 0) {
        #pragma unroll
        for (int c = 0; c < 6; ++c) ush[t >> 6][c] = u[c];
    }
    __syncthreads();
    if (t == 0) {
        float uu[6];
        #pragma unroll
        for (int c = 0; c < 6; ++c) uu[c] = ush[0][c] + ush[1][c] + bb_b[c];
        float inq = rsqrtf(1.0f + uu[0]*uu[0] + uu[1]*uu[1] + uu[2]*uu[2]);
        float w = inq, x = uu[0]*inq, y = uu[1]*inq, z = uu[2]*inq;
        float Ru[9];
        Ru[0] = 1.f - 2.f*(y*y + z*z); Ru[1] = 2.f*(x*y - w*z); Ru[2] = 2.f*(x*z + w*y);
        Ru[3] = 2.f*(x*y + w*z); Ru[4] = 1.f - 2.f*(x*x + z*z); Ru[5] = 2.f*(y*z - w*x);
        Ru[6] = 2.f*(x*z - w*y); Ru[7] = 2.f*(y*z + w*x); Ru[8] = 1.f - 2.f*(x*x + y*y);
        const float* R = rot + i * 9;
        #pragma unroll
        for (int a = 0; a < 3; ++a) {
            #pragma unroll
            for (int cc = 0; cc < 3; ++cc)
                out_rot[i * 9 + a * 3 + cc] =
                    R[a*3+0]*Ru[0+cc] + R[a*3+1]*Ru[3+cc] + R[a*3+2]*Ru[6+cc];
            out_trans[i * 3 + a] = R[a*3+0]*uu[3] + R[a*3+1]*uu[4] + R[a*3+2]*uu[5]
                                   + trans[i * 3 + a];
        }
    }
}

// ============ postproj: reduce proj partials + rotate points + emit Qext/Kext/Vext ========
__global__ __launch_bounds__(256) void postproj_kernel(
    const float* __restrict__ parts, const float* __restrict__ biasp,
    const float* __restrict__ rot, const float* __restrict__ trans,
    const float* __restrict__ head_w, const float* __restrict__ mask,
    ushort_t* __restrict__ Qext, ushort_t* __restrict__ Kext, ushort_t* __restrict__ Vext)
{
    __shared__ float buf[1152];
    __shared__ float hwv[12], kc28[12];
    const int j = blockIdx.x, t = threadIdx.x;
    for (int c = t; c < 1152; c += 256)
        buf[c] = biasp[c] + parts[(size_t)j * 1152 + c] + parts[(size_t)(512 + j) * 1152 + c];
    if (t >= 192 && t < 204) {
        int h = t - 192;
        hwv[h] = HW_SC * log1pf(expf(head_w[h]));
    }
    __syncthreads();
    if (t < 192) {
        int base = 576 + t * 3;
        const float* R = rot + j * 9;
        const float* T = trans + j * 3;
        float x = buf[base], y = buf[base + 1], z = buf[base + 2];
        float nx = R[0]*x + R[1]*y + R[2]*z + T[0];
        float ny = R[3]*x + R[4]*y + R[5]*z + T[1];
        float nz = R[6]*x + R[7]*y + R[8]*z + T[2];
        buf[base] = nx; buf[base + 1] = ny; buf[base + 2] = nz;
    }
    __syncthreads();
    if (t < 12) {
        float s2 = 0.f;
        #pragma unroll
        for (int e = 0; e < 12; ++e) { float v = buf[720 + t * 36 + e]; s2 += v * v; }
        kc28[t] = -0.5f * hwv[t] * s2 + (mask[j] - 1.0f) * INFV;
    }
    __syncthreads();
    if (t < 192) {
        int h = t >> 4, c0 = (t & 15) * 2;
        float hwf = hwv[h];
        #pragma unroll
        for (int e = 0; e < 2; ++e) {
            int c = c0 + e;
            float qv, kv2;
            if (c < 16)      { qv = SC_QK * buf[h * 16 + c];           kv2 = buf[192 + h * 32 + c]; }
            else if (c < 28) { qv = hwf * buf[576 + h * 12 + (c - 16)]; kv2 = buf[720 + h * 36 + (c - 16)]; }
            else if (c == 28){ qv = 1.f;                               kv2 = kc28[h]; }
            else             { qv = 0.f;                               kv2 = 0.f; }
            Qext[(size_t)h * 16384 + j * 32 + c] = (ushort_t)f2bf(qv);
            Kext[(size_t)h * 16384 + j * 32 + c] = (ushort_t)f2bf(kv2);
        }
    }
    for (int idx = t; idx < 576; idx += 256) {
        int h = idx / 48, c = idx % 48;
        float v;
        if (c < 16)      v = buf[192 + h * 32 + 16 + c];
        else if (c < 40) v = buf[720 + h * 36 + 12 + (c - 16)];
        else             v = 0.f;
        Vext[(size_t)h * 24576 + c * 512 + j] = (ushort_t)f2bf(v);
    }
}

// ============ qk logits: qk_b[i][j][16] = Qext_h[i] . Kext_h[j], bf16 ============
__global__ __launch_bounds__(256) void qk_kernel(
    const ushort_t* __restrict__ Qext, const ushort_t* __restrict__ Kext,
    ushort_t* __restrict__ qk_b)
{
    const int t = threadIdx.x, w = t >> 6, l = t & 63;
    const int i0 = blockIdx.x * 16, h = blockIdx.y;
    const int lr = l & 15, hk = l >> 4;
    bf16x8 a0 = *(const bf16x8*)(Qext + (size_t)h * 16384 + (i0 + lr) * 32 + hk * 8);
    #pragma unroll
    for (int n = 0; n < 8; ++n) {
        bf16x8 b = *(const bf16x8*)(Kext + (size_t)h * 16384 +
                                    (w * 128 + n * 16 + lr) * 32 + hk * 8);
        f32x4 acc = __builtin_amdgcn_mfma_f32_16x16x32_bf16(
                        a0, b, (f32x4){0.f, 0.f, 0.f, 0.f}, 0, 0, 0);
        int j = w * 128 + n * 16 + lr;
        #pragma unroll
        for (int r = 0; r < 4; ++r) {
            int i = i0 + hk * 4 + r;
            qk_b[((size_t)i * 512 + j) * 16 + h] = (ushort_t)f2bf(acc[r]);
        }
    }
}

// ============ mega attention: bias + qk + online softmax + o_pair, ONE p pass =========
// block = one query row i (512 blocks). Loops 8 j-tiles of 64.
__global__ __launch_bounds__(256) void mega_attn(
    const float* __restrict__ p, const ushort_t* __restrict__ qk_b,
    const float* __restrict__ w_b, const float* __restrict__ b_b,
    ushort_t* __restrict__ attn_b, ushort_t* __restrict__ catb)
{
    __shared__ __align__(16) ushort_t Wbs[16 * 128];     // 4 KB (SC_B folded)
    __shared__ __align__(16) ushort_t Pr[64 * 128];      // 16 KB row-major bf16, swz
    __shared__ __align__(16) ushort_t Pt[128 * 72];      // 18 KB transposed, swz
    __shared__ __align__(16) ushort_t qkT[64 * 16];      // 2 KB: [j][h]
    __shared__ __align__(16) ushort_t wT[16 * 64];       // 2 KB
    __shared__ __align__(16) ushort_t wFull[16 * 512];   // 16 KB
    __shared__ float mTile[16][8];
    __shared__ float redw[4][16], redw2[4][16];
    __shared__ float fArr[16], lArr[16], mArr[16];

    const int t = threadIdx.x, i = blockIdx.x;
    const int w = t >> 6, l = t & 63, lr = l & 15, hk = l >> 4;

    // Wbs: B^T for bias, SC_B folded, rows 12..15 zero
    for (int idx = t; idx < 2048; idx += 256) {
        int h = idx >> 7, c = idx & 127;
        float v = (h < 12) ? SC_B * w_b[c * 12 + h] : 0.f;
        *(ushort_t*)((char*)Wbs + h * 256 + ((c * 2) ^ ((h & 7) << 4))) = (ushort_t)f2bf(v);
    }
    const float sc_bb = (lr < 12) ? SC_B * b_b[lr] : 0.f;

    const float* psrc = p + (size_t)i * 65536;
    const int jA = (t >> 3) * 2, c0 = (t & 7) * 16;

    f32x4 va[4], vb[4];
    #define LOAD_REGS(tile)                                                      \
        {                                                                        \
            const float* s0 = psrc + (size_t)((tile) * 64 + jA) * 128 + c0;      \
            _Pragma("unroll")                                                    \
            for (int q = 0; q < 4; ++q) {                                        \
                va[q] = *(const f32x4*)(s0 + q * 4);                             \
                vb[q] = *(const f32x4*)(s0 + 128 + q * 4);                       \
            }                                                                    \
        }
    #define WRITE_BUFS()                                                         \
        {                                                                        \
            _Pragma("unroll")                                                    \
            for (int r2 = 0; r2 < 2; ++r2) {                                     \
                int j = jA + r2;                                                 \
                const f32x4* vr = r2 ? vb : va;                                  \
                _Pragma("unroll")                                                \
                for (int half = 0; half < 2; ++half) {                           \
                    u32x4 pk;                                                    \
                    pk[0] = cvtpk(vr[half*2][0], vr[half*2][1]);                 \
                    pk[1] = cvtpk(vr[half*2][2], vr[half*2][3]);                 \
                    pk[2] = cvtpk(vr[half*2+1][0], vr[half*2+1][1]);             \
                    pk[3] = cvtpk(vr[half*2+1][2], vr[half*2+1][3]);             \
                    int byte = j * 256 + (((c0 + half * 8) * 2) ^ ((j & 7) << 4));\
                    *(u32x4*)((char*)Pr + byte) = pk;                            \
                }                                                                \
            }                                                                    \
            _Pragma("unroll")                                                    \
            for (int e = 0; e < 16; ++e) {                                       \
                int c = c0 + e;                                                  \
                unsigned pk = cvtpk(va[e >> 2][e & 3], vb[e >> 2][e & 3]);       \
                int byte = c * 144 + ((jA * 2) ^ (((c >> 4) & 7) << 4));         \
                *(unsigned*)((char*)Pt + byte) = pk;                             \
            }                                                                    \
        }
    #define STAGE_QK(tile)                                                      \
        if (t < 128)                                                            \
            gload16(qk_b + ((size_t)i * 512 + (tile) * 64) * 16 + t * 8,        \
                    (char*)qkT + t * 16);

    LOAD_REGS(0);
    STAGE_QK(0);
    __syncthreads();          // Wbs done
    WRITE_BUFS();             // tile 0 -> Pr/Pt
    LOAD_REGS(1);
    float m_reg = -3.0e38f, l_reg = 0.f;
    f32x4 accP[2];
    accP[0] = (f32x4){0.f, 0.f, 0.f, 0.f};
    accP[1] = (f32x4){0.f, 0.f, 0.f, 0.f};
    __syncthreads();          // Pr/Pt(0) + qkT(0) ready (vmcnt drained)

    const int jl2 = w * 16 + lr;   // A-frag row (j within tile)
    for (int tile = 0; tile < 8; ++tile) {
        // ---- bias logits: out rows j (M), cols h (N); K=128 over pair channels ----
        f32x4 S = (f32x4){0.f, 0.f, 0.f, 0.f};
        #pragma unroll
        for (int ks = 0; ks < 4; ++ks) {
            bf16x8 afr = *(const bf16x8*)((char*)Pr + jl2 * 256 +
                            ((ks * 64 + hk * 16) ^ ((jl2 & 7) << 4)));
            bf16x8 bfr = *(const bf16x8*)((char*)Wbs + lr * 256 +
                            ((ks * 64 + hk * 16) ^ ((lr & 7) << 4)));
            S = __builtin_amdgcn_mfma_f32_16x16x32_bf16(afr, bfr, S, 0, 0, 0);
        }
        // S element r: row j = w*16 + hk*4 + r, col h = lr; add sc_bb + qk
        float sv[4];
        float tmax = -3.0e38f;
        #pragma unroll
        for (int r = 0; r < 4; ++r) {
            int jloc = w * 16 + hk * 4 + r;
            float qkv = (lr < 12) ? bf2f(qkT[jloc * 16 + lr]) : 0.f;
            sv[r] = S[r] + sc_bb + qkv;
            tmax = fmaxf(tmax, sv[r]);
        }
        tmax = fmaxf(tmax, __shfl_xor(tmax, 16));
        tmax = fmaxf(tmax, __shfl_xor(tmax, 32));
        if (hk == 0) redw[w][lr] = tmax;
        __syncthreads();                                  // (a)
        if (tile < 7) STAGE_QK(tile + 1);                 // qkT consumed; refill
        float mt = fmaxf(fmaxf(redw[0][lr], redw[1][lr]),
                         fmaxf(redw[2][lr], redw[3][lr]));
        float m_new = fmaxf(m_reg, mt);
        float f = __expf(m_reg - m_new);
        m_reg = m_new;
        float tsum = 0.f;
        ushort_t wv16[4];
        #pragma unroll
        for (int r = 0; r < 4; ++r) {
            float wv = __expf(sv[r] - m_new);
            tsum += wv;
            wv16[r] = (ushort_t)f2bf(wv);
        }
        tsum += __shfl_xor(tsum, 16);
        tsum += __shfl_xor(tsum, 32);
        if (hk == 0) redw2[w][lr] = tsum;
        if (w == 0 && hk == 0) { fArr[lr] = f; mTile[lr][tile] = m_new; }
        #pragma unroll
        for (int r = 0; r < 4; ++r) {
            int j = w * 16 + hk * 4 + r;
            *(ushort_t*)((char*)wT + lr * 128 + ((j * 2) ^ ((lr & 7) << 4))) = wv16[r];
            int jg = tile * 64 + j;
            *(ushort_t*)((char*)wFull + lr * 1024 + ((jg * 2) ^ ((lr & 7) << 4))) = wv16[r];
        }
        __syncthreads();                                  // (b)
        float sumAll = redw2[0][lr] + redw2[1][lr] + redw2[2][lr] + redw2[3][lr];
        l_reg = l_reg * f + sumAll;
        // rescale o_pair accumulator (rows h = hk*4 + r) and add this tile
        #pragma unroll
        for (int n = 0; n < 2; ++n)
            #pragma unroll
            for (int r = 0; r < 4; ++r) accP[n][r] *= fArr[hk * 4 + r];
        #pragma unroll
        for (int ks = 0; ks < 2; ++ks) {
            bf16x8 afr = *(const bf16x8*)((char*)wT + lr * 128 +
                            ((ks * 64 + hk * 16) ^ ((lr & 7) << 4)));
            #pragma unroll
            for (int n = 0; n < 2; ++n) {
                int c = w * 32 + n * 16 + lr;
                bf16x8 bfr = *(const bf16x8*)((char*)Pt + c * 144 +
                                ((ks * 64 + hk * 16) ^ (((c >> 4) & 7) << 4)));
                accP[n] = __builtin_amdgcn_mfma_f32_16x16x32_bf16(afr, bfr, accP[n], 0, 0, 0);
            }
        }
        __syncthreads();                                  // (c) Pr/Pt/wT consumed
        if (tile < 7) {
            WRITE_BUFS();                                 // tile+1 -> Pr/Pt
            if (tile < 6) LOAD_REGS(tile + 2);
        }
        __syncthreads();                                  // (d) bufs + qkT ready
    }
    #undef LOAD_REGS
    #undef WRITE_BUFS
    #undef STAGE_QK

    if (w == 0 && hk == 0) { lArr[lr] = l_reg; mArr[lr] = m_reg; }
    __syncthreads();

    // o_pair write
    #pragma unroll
    for (int n = 0; n < 2; ++n) {
        int c = w * 32 + n * 16 + lr;
        #pragma unroll
        for (int r = 0; r < 4; ++r) {
            int h = hk * 4 + r;
            if (h < 12)
                catb[(size_t)i * DCAT + 576 + h * 128 + c] =
                    (ushort_t)f2bf(accP[n][r] / lArr[h]);
        }
    }
    // normalized attention weights -> attn_b
    {
        int h = t >> 4;
        if (h < 12) {
            float linv = 1.0f / lArr[h];
            float mfin = mArr[h];
            #pragma unroll
            for (int e = 0; e < 4; ++e) {
                int cp = (t & 15) * 4 + e;        // phys 16B chunk within row
                int jc = cp ^ (h & 7);            // logical chunk (8 j)
                int j0 = jc * 8;
                float corr = __expf(mTile[h][j0 >> 6] - mfin) * linv;
                bf16x8 raw = *(const bf16x8*)((char*)wFull + h * 1024 + cp * 16);
                bf16x8 o;
                #pragma unroll
                for (int q = 0; q < 8; ++q)
                    o[q] = (short)f2bf(bf2f((ushort_t)raw[q]) * corr);
                *(bf16x8*)(attn_b + (size_t)h * NN + (size_t)i * 512 + j0) = o;
            }
        }
    }
}

// ============ O = A @ [v|vp] via MFMA + fused op finalize; 1 wave per (16 i, h) ============
__global__ __launch_bounds__(64) void ov_mfma(
    const ushort_t* __restrict__ attn_b, const ushort_t* __restrict__ Vext,
    const float* __restrict__ rot, const float* __restrict__ trans,
    ushort_t* __restrict__ catb)
{
    __shared__ float opl[16][25];
    const int l = threadIdx.x;
    const int i0 = blockIdx.x * 16, h = blockIdx.y;
    const int lr = l & 15, hk = l >> 4;
    f32x4 acc[3];
    acc[0] = (f32x4){0.f,0.f,0.f,0.f};
    acc[1] = (f32x4){0.f,0.f,0.f,0.f};
    acc[2] = (f32x4){0.f,0.f,0.f,0.f};
    const ushort_t* arow = attn_b + (size_t)h * NN + (size_t)(i0 + lr) * 512 + hk * 8;
    const ushort_t* vbase = Vext + (size_t)h * 24576 + lr * 512 + hk * 8;
    #pragma unroll
    for (int kt = 0; kt < 16; ++kt) {
        bf16x8 af = *(const bf16x8*)(arow + kt * 32);
        #pragma unroll
        for (int n = 0; n < 3; ++n) {
            bf16x8 bf = *(const bf16x8*)(vbase + n * 16 * 512 + kt * 32);
            acc[n] = __builtin_amdgcn_mfma_f32_16x16x32_bf16(af, bf, acc[n], 0, 0, 0);
        }
    }
    #pragma unroll
    for (int n = 0; n < 3; ++n) {
        int c = n * 16 + lr;
        #pragma unroll
        for (int r = 0; r < 4; ++r) {
            int ri = hk * 4 + r;
            if (c < 16)
                catb[(size_t)(i0 + ri) * DCAT + h * 16 + c] = (ushort_t)f2bf(acc[n][r]);
            else if (c < 40)
                opl[ri][c - 16] = acc[n][r];
        }
    }
    __syncthreads();
    #pragma unroll
    for (int e = 0; e < 2; ++e) {
        int pt = l + e * 64;
        int i16 = pt >> 3, pv = pt & 7;
        int i = i0 + i16;
        const float* T = trans + i * 3;
        const float* R = rot + i * 9;
        float x = opl[i16][pv * 3 + 0] - T[0];
        float y = opl[i16][pv * 3 + 1] - T[1];
        float z = opl[i16][pv * 3 + 2] - T[2];
        float rx = R[0] * x + R[3] * y + R[6] * z;
        float ry = R[1] * x + R[4] * y + R[7] * z;
        float rz = R[2] * x + R[5] * y + R[8] * z;
        float nm = sqrtf(rx * rx + ry * ry + rz * rz + 1e-8f);
        ushort_t* cr = catb + (size_t)i * DCAT;
        cr[192 + h * 24 + pv * 3 + 0] = (ushort_t)f2bf(rx);
        cr[192 + h * 24 + pv * 3 + 1] = (ushort_t)f2bf(ry);
        cr[192 + h * 24 + pv * 3 + 2] = (ushort_t)f2bf(rz);
        cr[480 + h * 8 + pv] = (ushort_t)f2bf(nm);
    }
}

extern "C" void kernel_launch(void* const* d_in, const int* in_sizes, int n_in,
                              void* d_out, int out_size, void* d_ws, size_t ws_size,
                              hipStream_t stream)
{
    const float* s      = (const float*)d_in[0];
    const float* p      = (const float*)d_in[1];
    const float* rot    = (const float*)d_in[2];
    const float* trans  = (const float*)d_in[3];
    const float* mask   = (const float*)d_in[4];
    const float* w_q    = (const float*)d_in[5];
    const float* b_q    = (const float*)d_in[6];
    const float* w_kv   = (const float*)d_in[7];
    const float* b_kv   = (const float*)d_in[8];
    const float* w_qp   = (const float*)d_in[9];
    const float* b_qp   = (const float*)d_in[10];
    const float* w_kvp  = (const float*)d_in[11];
    const float* b_kvp  = (const float*)d_in[12];
    const float* w_b    = (const float*)d_in[13];
    const float* b_b    = (const float*)d_in[14];
    const float* head_w = (const float*)d_in[15];
    const float* w_o    = (const float*)d_in[16];
    const float* b_o    = (const float*)d_in[17];
    const float* ln1_g  = (const float*)d_in[18];
    const float* ln1_b  = (const float*)d_in[19];
    const float* tw1    = (const float*)d_in[20];
    const float* tb1    = (const float*)d_in[21];
    const float* tw2    = (const float*)d_in[22];
    const float* tb2    = (const float*)d_in[23];
    const float* tw3    = (const float*)d_in[24];
    const float* tb3    = (const float*)d_in[25];
    const float* ln2_g  = (const float*)d_in[26];
    const float* ln2_b  = (const float*)d_in[27];
    const float* bb_w   = (const float*)d_in[28];
    const float* bb_b   = (const float*)d_in[29];

    float* ws = (float*)d_ws;
    float*    parts  = ws;                       // 1179648
    float*    partsB = parts + 589824;           // gemm_red ping-pong
    float*    s1     = parts + 1179648;          // 196608
    float*    biasp  = s1 + 196608;              // 1152
    ushort_t* ub     = (ushort_t*)(biasp + 1152);
    ushort_t* attn_b = ub;                       // 3145728
    ushort_t* catb   = attn_b + 3145728;         // 1081344
    ushort_t* sbf    = catb + 1081344;           // 196608
    ushort_t* s1bf   = sbf + 196608;
    ushort_t* Qext   = s1bf + 196608;            // 196608
    ushort_t* Kext   = Qext + 196608;            // 196608
    ushort_t* Vext   = Kext + 196608;            // 294912
    ushort_t* Wtp    = Vext + 294912;            // 442368
    ushort_t* Wto    = Wtp + 442368;             // 811008
    ushort_t* Wt1    = Wto + 811008;             // 147456
    ushort_t* Wt2    = Wt1 + 147456;
    ushort_t* Wt3    = Wt2 + 147456;
    ushort_t* qk_b   = Wt3 + 147456;             // 4194304 (8 MB) [i][j][16]

    float* out_s     = (float*)d_out;
    float* out_rot   = out_s + 196608;
    float* out_trans = out_rot + 4608;

    // ---- prep ----
    PrepArgs pa;
    pa.wsrc0 = w_q;  pa.wdst0 = Wtp;
    pa.wsrc1 = w_kv; pa.wdst1 = Wtp + (size_t)192 * 384;
    pa.wsrc2 = w_qp; pa.wdst2 = Wtp + (size_t)576 * 384;
    pa.wsrc3 = w_kvp; pa.wdst3 = Wtp + (size_t)720 * 384;
    pa.wsrc4 = w_o;  pa.wdst4 = Wto;
    pa.wsrc5 = tw1;  pa.wdst5 = Wt1;
    pa.wsrc6 = tw2;  pa.wdst6 = Wt2;
    pa.wsrc7 = tw3;  pa.wdst7 = Wt3;
    pa.s = s; pa.sbf = sbf;
    pa.bq = b_q; pa.bkv = b_kv; pa.bqp = b_qp; pa.bkvp = b_kvp;
    pa.biasp = biasp;
    prep_kernel<<<1861, 256, 0, stream>>>(pa);

    // ---- projection GEMM + fused post-processing ----
    gemm_bf16<<<dim3(8, 18, 2), 256, 0, stream>>>(sbf, Wtp, parts, 384, 1152, 6);
    postproj_kernel<<<512, 256, 0, stream>>>(parts, biasp, rot, trans, head_w, mask,
                                             Qext, Kext, Vext);

    // ---- attention: qk precompute, then single-pass p mega, then o ----
    qk_kernel<<<dim3(32, 12), 256, 0, stream>>>(Qext, Kext, qk_b);
    mega_attn<<<512, 256, 0, stream>>>(p, qk_b, w_b, b_b, attn_b, catb);
    ov_mfma<<<dim3(32, 12), 64, 0, stream>>>(attn_b, Vext, rot, trans, catb);

    // ---- output projection + residual + LN1 ----
    gemm_bf16<<<dim3(8, 6, 6), 256, 0, stream>>>(catb, Wto, parts, 2112, 384, 11);
    reduce_ln<<<512, 128, 0, stream>>>(parts, 6, b_o, s, ln1_g, ln1_b, s1, s1bf,
                                       nullptr, nullptr, nullptr, nullptr, nullptr, nullptr);

    // ---- transition ----
    gemm_bf16<<<dim3(8, 6, 3), 256, 0, stream>>>(s1bf, Wt1, parts, 384, 384, 4);
    gemm_red<<<dim3(8, 6, 3), 256, 0, stream>>>(parts, tb1, Wt2, partsB, 4);
    gemm_red<<<dim3(8, 6, 3), 256, 0, stream>>>(partsB, tb2, Wt3, parts, 4);
    reduce_ln<<<512, 128, 0, stream>>>(parts, 3, tb3, s1, ln2_g, ln2_b, out_s, nullptr,
                                       bb_w, bb_b, rot, trans, out_rot, out_trans);
}